// Round 15
// baseline (173.947 us; speedup 1.0000x reference)
//
#include <hip/hip_runtime.h>
#include <math.h>

// ProGAT: B=8,S=512,NB=23,INIT=512,E=256,R=3,T=2
// R15: 13 dispatches. Round = gagh (gatherattend || gh-GEMM fat) + gi GEMM
// + grudot. Tail = seqpvtf (tf tile via MFMA + softmax + PV in one kernel)
// + seqstep x2. Head unchanged from R14.

#define BSZ   8
#define SEQ   512
#define NBR   23
#define EMB   256
#define INITD 512
#define BS    (BSZ*SEQ)     // 4096
#define G3    (3*EMB)       // 768
#define NEGV  -9e8f

typedef __attribute__((ext_vector_type(8))) short short8;
typedef __attribute__((ext_vector_type(4))) float f32x4;

__device__ __forceinline__ float lrelu(float x){ return x > 0.f ? x : 0.01f*x; }
__device__ __forceinline__ float elu1 (float x){ return x > 0.f ? x : (expf(x)-1.f); }
__device__ __forceinline__ float sigm (float x){ return 1.f/(1.f+expf(-x)); }
__device__ __forceinline__ float bf2f(ushort u){
    union { unsigned int i; float f; } v; v.i = ((unsigned int)u) << 16; return v.f;
}
__device__ __forceinline__ ushort f2bf(float f){
    union { float f; unsigned int i; } v; v.f = f;
    unsigned int u = v.i;
    return (ushort)((u + 0x7FFFu + ((u >> 16) & 1u)) >> 16);   // RNE
}
__device__ __forceinline__ unsigned pk2(float a, float b){
    return (unsigned)f2bf(a) | ((unsigned)f2bf(b) << 16);
}
__device__ __forceinline__ void unpack8(uint4 v, float* o) {
    o[0]=bf2f((ushort)(v.x&0xffff)); o[1]=bf2f((ushort)(v.x>>16));
    o[2]=bf2f((ushort)(v.y&0xffff)); o[3]=bf2f((ushort)(v.y>>16));
    o[4]=bf2f((ushort)(v.z&0xffff)); o[5]=bf2f((ushort)(v.z>>16));
    o[6]=bf2f((ushort)(v.w&0xffff)); o[7]=bf2f((ushort)(v.w>>16));
}

__device__ __forceinline__ void gload_lds16(const void* g, void* l) {
    __builtin_amdgcn_global_load_lds(
        (const __attribute__((address_space(1))) unsigned int*)g,
        (__attribute__((address_space(3))) unsigned int*)l,
        16, 0, 0);
}

// ---- balanced flat converter: 9 bf16 segments + seqfeat zero-fill.
__global__ __launch_bounds__(256) void convert_flat(
    const float* __restrict__ amino, ushort* __restrict__ aminobf,
    const float* __restrict__ embW,  ushort* __restrict__ embWbf,
    const float* __restrict__ nbW,   ushort* __restrict__ nbWbf,
    const float* __restrict__ attW,  ushort* __restrict__ attWbf,
    const float* __restrict__ gwih,  ushort* __restrict__ gwihbf,
    const float* __restrict__ gwhh,  ushort* __restrict__ gwhhbf,
    const float* __restrict__ satW,  ushort* __restrict__ satWbf,
    const float* __restrict__ sgwih, ushort* __restrict__ sgwihbf,
    const float* __restrict__ sgwhh, ushort* __restrict__ sgwhhbf,
    float* __restrict__ seqfeatZ)
{
    const unsigned stride = gridDim.x * 256;
    for (unsigned u = blockIdx.x*256 + threadIdx.x; u < 524544u; u += stride) {
        const float* s; ushort* d; unsigned lu;
        if      (u < 262144u) { s=amino; d=aminobf; lu=u; }
        else if (u < 278528u) { s=embW;  d=embWbf;  lu=u-262144u; }
        else if (u < 294912u) { s=nbW;   d=nbWbf;   lu=u-278528u; }
        else if (u < 319488u) { s=attW;  d=attWbf;  lu=u-294912u; }
        else if (u < 393216u) { s=gwih;  d=gwihbf;  lu=u-319488u; }
        else if (u < 466944u) { s=gwhh;  d=gwhhbf;  lu=u-393216u; }
        else if (u < 475136u) { s=satW;  d=satWbf;  lu=u-466944u; }
        else if (u < 499712u) { s=sgwih; d=sgwihbf; lu=u-475136u; }
        else if (u < 524288u) { s=sgwhh; d=sgwhhbf; lu=u-499712u; }
        else {
            unsigned i = (u - 524288u) * 8;
            *reinterpret_cast<float4*>(&seqfeatZ[i])     = make_float4(0,0,0,0);
            *reinterpret_cast<float4*>(&seqfeatZ[i + 4]) = make_float4(0,0,0,0);
            continue;
        }
        size_t i = (size_t)lu * 8;
        float4 a = *reinterpret_cast<const float4*>(s + i);
        float4 b = *reinterpret_cast<const float4*>(s + i + 4);
        uint4 o;
        o.x = pk2(a.x, a.y); o.y = pk2(a.z, a.w);
        o.z = pk2(b.x, b.y); o.w = pk2(b.z, b.w);
        *reinterpret_cast<uint4*>(d + i) = o;
    }
}

// ---- 128x64 MFMA GEMM; global_load_lds staging, dbuf (256 threads)
struct GemmLds64 { ushort A[2][128][64]; ushort B[2][64][64]; };

template<int ACT>
__device__ __forceinline__ void gemm64_dev(
    const ushort* __restrict__ A, const ushort* __restrict__ W,
    const float* __restrict__ bias,
    float* __restrict__ C, ushort* __restrict__ Cbf,
    int N, int K, int bx, int by, GemmLds64& L)
{
    const int tid = threadIdx.x;
    const int m0 = bx * 128, n0 = by * 64;
    const int wv = tid >> 6, lane = tid & 63;
    const int fr = lane & 15, grp = lane >> 4;
    const int kc = K >> 3;
    const int mh = wv & 1, nh = wv >> 1;
    const int lrow = lane >> 3;
    const int csrc = (lane & 7) ^ lrow;

    f32x4 acc[4][2];
    #pragma unroll
    for (int i = 0; i < 4; ++i)
        #pragma unroll
        for (int n = 0; n < 2; ++n) acc[i][n] = (f32x4){0.f,0.f,0.f,0.f};

    auto stage = [&](int c, int k0) {
        const int kch = (k0 >> 3) + csrc;
        #pragma unroll
        for (int i = 0; i < 4; ++i) {
            const int s = (wv << 2) + i;
            gload_lds16(A + ((size_t)(m0 + (s << 3) + lrow) * kc + kch) * 8,
                        &L.A[c][s << 3][0]);
        }
        #pragma unroll
        for (int i = 0; i < 2; ++i) {
            const int s = (wv << 1) + i;
            gload_lds16(W + ((size_t)(n0 + (s << 3) + lrow) * kc + kch) * 8,
                        &L.B[c][s << 3][0]);
        }
    };
    auto compute = [&](int c) {
        #pragma unroll
        for (int ks = 0; ks < 2; ++ks) {
            short8 af[4];
            #pragma unroll
            for (int i = 0; i < 4; ++i) {
                const int ar = (mh << 6) + (i << 4) + fr;
                af[i] = *reinterpret_cast<const short8*>(
                    &L.A[c][ar][(((ks << 2) + grp) ^ (ar & 7)) << 3]);
            }
            #pragma unroll
            for (int n = 0; n < 2; ++n) {
                const int br = (nh << 5) + (n << 4) + fr;
                short8 bv = *reinterpret_cast<const short8*>(
                    &L.B[c][br][(((ks << 2) + grp) ^ (br & 7)) << 3]);
                #pragma unroll
                for (int i = 0; i < 4; ++i)
                    acc[i][n] = __builtin_amdgcn_mfma_f32_16x16x32_bf16(
                        af[i], bv, acc[i][n], 0, 0, 0);
            }
        }
    };

    const int KT = K >> 6;
    stage(0, 0);
    __syncthreads();
    int cur = 0;
    for (int kt = 1; kt < KT; ++kt) {
        stage(cur ^ 1, kt << 6);
        compute(cur);
        __syncthreads();
        cur ^= 1;
    }
    compute(cur);

    #pragma unroll
    for (int i = 0; i < 4; ++i) {
        const int mrow = m0 + (mh << 6) + (i << 4) + (grp << 2);
        #pragma unroll
        for (int n = 0; n < 2; ++n) {
            const int col = n0 + (nh << 5) + (n << 4) + fr;
            const float bv = bias[col];
            #pragma unroll
            for (int j = 0; j < 4; ++j) {
                float t = acc[i][n][j] + bv;
                if (ACT == 1) t = lrelu(t);
                size_t off = (size_t)(mrow + j) * N + col;
                if (C)   C[off] = t;
                if (Cbf) Cbf[off] = f2bf(t);
            }
        }
    }
}

// ---- fat: feat GEMM (0..127) + nbase GEMM (128..255), K=512
__global__ __launch_bounds__(256) void featnbase_kernel(
    const ushort* __restrict__ aminobf,
    const ushort* __restrict__ embWbf, const float* __restrict__ embB,
    float* __restrict__ feat, ushort* __restrict__ featbf,
    const ushort* __restrict__ nbWbf, const float* __restrict__ nbB,
    float* __restrict__ nbase, ushort* __restrict__ nbasebf)
{
    __shared__ GemmLds64 L;
    int blk = blockIdx.x;
    if (blk < 128)
        gemm64_dev<1>(aminobf, embWbf, embB, feat, featbf, EMB, INITD, blk & 31, blk >> 5, L);
    else {
        blk -= 128;
        gemm64_dev<1>(aminobf, nbWbf, nbB, nbase, nbasebf, EMB, INITD, blk & 31, blk >> 5, L);
    }
}

// ---- dot2 for round 0: 128 blocks x 32 rows
__global__ __launch_bounds__(256) void dot2_kernel(
    const float* __restrict__ center, const float* __restrict__ nbrbase,
    const float* __restrict__ alignWd,
    float* __restrict__ cdot, float* __restrict__ ndot)
{
    const int lane = threadIdx.x & 63;
    const int wv   = threadIdx.x >> 6;
    const int e    = lane << 2;
    const int rb   = blockIdx.x * 32 + wv * 8;
    float4 w0 = *reinterpret_cast<const float4*>(&alignWd[e]);
    float4 w1 = *reinterpret_cast<const float4*>(&alignWd[EMB + e]);
    #pragma unroll
    for (int i = 0; i < 8; ++i) {
        const int r = rb + i;
        float4 xc = *reinterpret_cast<const float4*>(&center[(size_t)r*EMB + e]);
        float4 xn = *reinterpret_cast<const float4*>(&nbrbase[(size_t)r*EMB + e]);
        float ac = xc.x*w0.x + xc.y*w0.y + xc.z*w0.z + xc.w*w0.w;
        float an = xn.x*w1.x + xn.y*w1.y + xn.z*w1.z + xn.w*w1.w;
        #pragma unroll
        for (int off = 32; off; off >>= 1) {
            ac += __shfl_xor(ac, off, 64);
            an += __shfl_xor(an, off, 64);
        }
        if (lane == 0) { cdot[r] = ac; ndot[r] = an; }
    }
}

// ---- gatherattend (256-thread version): gather + attend MFMA -> ctxbf
struct GALds { ushort ctxpre[16][256]; ushort ctx[16][256]; float wsum_s[16]; };
union RoundLds { GALds ga; GemmLds64 g; };

__device__ __forceinline__ void gatherattend_dev(
    int blk,
    const float* __restrict__ cdot, const float* __restrict__ ndot,
    const int* __restrict__ idx, const ushort* __restrict__ nbr,
    const float* __restrict__ alignBd,
    const ushort* __restrict__ attWd, const float* __restrict__ attBd,
    ushort* __restrict__ ctxbf, GALds& L)
{
    const int tid = threadIdx.x;
    const int r0 = blk * 16;

    // gather: 8 row-groups x 32 lanes, 2 halves
    #pragma unroll
    for (int half = 0; half < 2; ++half) {
        const int row16 = (tid >> 5) + half*8, sub = tid & 31;
        const int r = r0 + row16, b = r >> 9;
        float sc = -3e38f, vm = 0.f; int rn = 0;
        if (sub < NBR) {
            int j = idx[(size_t)r*NBR + sub];
            int valid = (j >= 0);
            int jj = valid ? j : j + SEQ;   // JAX wrap: f[-1] = last row
            rn = b*SEQ + jj;
            vm = (float)valid;
            sc = lrelu(cdot[r] + ndot[rn] + alignBd[0]) + (valid ? 0.f : NEGV);
        }
        float m = sc;
        #pragma unroll
        for (int off = 16; off; off >>= 1) m = fmaxf(m, __shfl_xor(m, off, 32));
        float ev = (sub < NBR) ? expf(sc - m) : 0.f;
        float s = ev;
        #pragma unroll
        for (int off = 16; off; off >>= 1) s += __shfl_xor(s, off, 32);
        float wgt = ev * vm / s;
        float ws = wgt;
        #pragma unroll
        for (int off = 16; off; off >>= 1) ws += __shfl_xor(ws, off, 32);
        float a8[8] = {};
        const int e0 = sub << 3;
        #pragma unroll
        for (int n = 0; n < NBR; ++n) {
            float wn = __shfl(wgt, n, 32);
            int   rr = __shfl(rn, n, 32);
            uint4 v = *reinterpret_cast<const uint4*>(&nbr[(size_t)rr*EMB + e0]);
            float x[8]; unpack8(v, x);
            #pragma unroll
            for (int i = 0; i < 8; ++i) a8[i] += wn * x[i];
        }
        uint4 o;
        o.x = pk2(a8[0],a8[1]); o.y = pk2(a8[2],a8[3]);
        o.z = pk2(a8[4],a8[5]); o.w = pk2(a8[6],a8[7]);
        *reinterpret_cast<uint4*>(&L.ctxpre[row16][(sub ^ (row16&7)) << 3]) = o;
        if (sub == 0) L.wsum_s[row16] = ws;
    }
    __syncthreads();

    const int wv = tid >> 6, lane = tid & 63;
    const int fr = lane & 15, grp = lane >> 4;
    {   // attend MFMA: 4 waves x 64 cols (4 frags)
        f32x4 acc[4];
        #pragma unroll
        for (int f = 0; f < 4; ++f) acc[f] = (f32x4){0,0,0,0};
        #pragma unroll
        for (int kt = 0; kt < 8; ++kt) {
            short8 af = *reinterpret_cast<const short8*>(
                &L.ctxpre[fr][((((kt<<2)+grp) ^ (fr&7)) << 3)]);
            #pragma unroll
            for (int f = 0; f < 4; ++f) {
                const int col = (wv<<6) + (f<<4) + fr;
                short8 bv = *reinterpret_cast<const short8*>(
                    &attWd[(size_t)col*EMB + (kt<<5) + (grp<<3)]);
                acc[f] = __builtin_amdgcn_mfma_f32_16x16x32_bf16(af, bv, acc[f], 0, 0, 0);
            }
        }
        #pragma unroll
        for (int f = 0; f < 4; ++f) {
            const int col = (wv<<6) + (f<<4) + fr;
            const float bb = attBd[col];
            #pragma unroll
            for (int j = 0; j < 4; ++j) {
                const int row = (grp<<2) + j;
                L.ctx[row][col] = f2bf(elu1(acc[f][j] + L.wsum_s[row]*bb));
            }
        }
    }
    __syncthreads();
    {   // coalesced copy out: 512 uint4 over 256 threads, 2 iterations
        #pragma unroll
        for (int half = 0; half < 2; ++half) {
            const int row = (tid >> 5) + half*8, c = tid & 31;
            uint4 v = *reinterpret_cast<const uint4*>(&L.ctx[row][c << 3]);
            *reinterpret_cast<uint4*>(&ctxbf[(size_t)(r0+row)*EMB + (c << 3)]) = v;
        }
    }
}

// ---- fat round D1: gatherattend (0..255) || gh GEMM (256..639)
__global__ __launch_bounds__(256) void gagh_kernel(
    const float* __restrict__ cdot, const float* __restrict__ ndot,
    const int* __restrict__ idx, const ushort* __restrict__ nbr,
    const float* __restrict__ alignBd,
    const ushort* __restrict__ attWd, const float* __restrict__ attBd,
    ushort* __restrict__ ctxbf,
    const ushort* __restrict__ hprevbf, const ushort* __restrict__ gwhhd,
    const float* __restrict__ gbhhd, ushort* __restrict__ ghbf)
{
    __shared__ RoundLds L;
    if (blockIdx.x < 256) {
        gatherattend_dev(blockIdx.x, cdot, ndot, idx, nbr, alignBd,
                         attWd, attBd, ctxbf, L.ga);
    } else {
        int blk = blockIdx.x - 256;
        gemm64_dev<0>(hprevbf, gwhhd, gbhhd, nullptr, ghbf,
                      G3, EMB, blk & 31, blk >> 5, L.g);
    }
}

// ---- round D2: gi GEMM (384 blocks)
__global__ __launch_bounds__(256) void gi_kernel(
    const ushort* __restrict__ ctxbf, const ushort* __restrict__ gwihd,
    const float* __restrict__ gbihd, ushort* __restrict__ gibf)
{
    __shared__ GemmLds64 L;
    gemm64_dev<0>(ctxbf, gwihd, gbihd, nullptr, gibf, G3, EMB,
                  blockIdx.x & 31, blockIdx.x >> 5, L);
}

// ---- round D3: GRU (bf16 state) + next-round dot2 (or seq ad if LAST).
// LAST: f32 act out + atomic seqfeat accumulation.
template<int LAST>
__global__ __launch_bounds__(512) void grudot_kernel(
    const ushort* __restrict__ gibf, const ushort* __restrict__ ghbf,
    const ushort* __restrict__ hprevbf, const float* __restrict__ nextW,
    const float* __restrict__ mask,
    ushort* __restrict__ hbf, float* __restrict__ actout,
    ushort* __restrict__ actbf,
    float* __restrict__ cdotO, float* __restrict__ ndotO,
    float* __restrict__ seqfeatA)
{
    __shared__ float sred[16][256];
    const int tid = threadIdx.x;
    const int row = tid >> 5, sub = tid & 31;
    const int e0 = sub << 3;
    const size_t r = (size_t)blockIdx.x * 16 + row;
    const size_t gb = r*G3;
    uint4 giA = *reinterpret_cast<const uint4*>(&gibf[gb + e0]);
    uint4 giB = *reinterpret_cast<const uint4*>(&gibf[gb + 256 + e0]);
    uint4 giC = *reinterpret_cast<const uint4*>(&gibf[gb + 512 + e0]);
    uint4 ghA = *reinterpret_cast<const uint4*>(&ghbf[gb + e0]);
    uint4 ghB = *reinterpret_cast<const uint4*>(&ghbf[gb + 256 + e0]);
    uint4 ghC = *reinterpret_cast<const uint4*>(&ghbf[gb + 512 + e0]);
    uint4 hpv = *reinterpret_cast<const uint4*>(&hprevbf[r*EMB + e0]);
    float ir_[8], iz_[8], in_[8], hr_[8], hz_[8], hn_[8], hp_[8];
    unpack8(giA, ir_); unpack8(giB, iz_); unpack8(giC, in_);
    unpack8(ghA, hr_); unpack8(ghB, hz_); unpack8(ghC, hn_);
    unpack8(hpv, hp_);
    float hv8[8], av8[8];
    #pragma unroll
    for (int i = 0; i < 8; ++i) {
        float rg = sigm(ir_[i] + hr_[i]);
        float z  = sigm(iz_[i] + hz_[i]);
        float n  = tanhf(in_[i] + rg*hn_[i]);
        hv8[i] = (1.f - z)*n + z*hp_[i];
        av8[i] = fmaxf(hv8[i], 0.f);
    }
    if (LAST) {
        *reinterpret_cast<float4*>(&actout[r*EMB + e0])     = make_float4(av8[0],av8[1],av8[2],av8[3]);
        *reinterpret_cast<float4*>(&actout[r*EMB + e0 + 4]) = make_float4(av8[4],av8[5],av8[6],av8[7]);
    }
    uint4 hb, ab;
    hb.x = pk2(hv8[0],hv8[1]); hb.y = pk2(hv8[2],hv8[3]);
    hb.z = pk2(hv8[4],hv8[5]); hb.w = pk2(hv8[6],hv8[7]);
    ab.x = pk2(av8[0],av8[1]); ab.y = pk2(av8[2],av8[3]);
    ab.z = pk2(av8[4],av8[5]); ab.w = pk2(av8[6],av8[7]);
    *reinterpret_cast<uint4*>(&hbf[r*EMB + e0])   = hb;
    *reinterpret_cast<uint4*>(&actbf[r*EMB + e0]) = ab;
    float pc = 0.f, pn = 0.f;
    float4 w1a = *reinterpret_cast<const float4*>(&nextW[EMB + e0]);
    float4 w1b = *reinterpret_cast<const float4*>(&nextW[EMB + e0 + 4]);
    pn = av8[0]*w1a.x + av8[1]*w1a.y + av8[2]*w1a.z + av8[3]*w1a.w
       + av8[4]*w1b.x + av8[5]*w1b.y + av8[6]*w1b.z + av8[7]*w1b.w;
    if (!LAST) {
        float4 w0a = *reinterpret_cast<const float4*>(&nextW[e0]);
        float4 w0b = *reinterpret_cast<const float4*>(&nextW[e0 + 4]);
        pc = av8[0]*w0a.x + av8[1]*w0a.y + av8[2]*w0a.z + av8[3]*w0a.w
           + av8[4]*w0b.x + av8[5]*w0b.y + av8[6]*w0b.z + av8[7]*w0b.w;
    }
    #pragma unroll
    for (int off = 16; off; off >>= 1) {
        pn += __shfl_xor(pn, off, 32);
        if (!LAST) pc += __shfl_xor(pc, off, 32);
    }
    if (sub == 0) {
        if (!LAST) cdotO[r] = pc;
        ndotO[r] = pn;
    }
    if (LAST) {
        const float mk = mask[r];
        #pragma unroll
        for (int i = 0; i < 8; ++i) sred[row][e0 + i] = av8[i] * mk;
        __syncthreads();
        if (tid < 256) {
            float s = 0.f;
            #pragma unroll
            for (int rr = 0; rr < 16; ++rr) s += sred[rr][tid];
            atomicAdd(&seqfeatA[(blockIdx.x >> 5)*EMB + tid], s);
        }
    }
}

// ---- seqpvtf: per-strip tf tile via MFMA + cmol + softmax + PV.
// Block (st, b): rows r0 = b*512 + st*32 .. +32. 256 threads.
__global__ __launch_bounds__(256) void seqpvtf_kernel(
    const float* __restrict__ ad, const float* __restrict__ mask,
    const float* __restrict__ saB, const float* __restrict__ saW,
    const float* __restrict__ seqfeat,
    const ushort* __restrict__ actbf, const ushort* __restrict__ satWbf,
    const float* __restrict__ satB,
    float* __restrict__ partial)
{
    const int st = blockIdx.x, b = blockIdx.y;
    const int tid = threadIdx.x;
    __shared__ ushort As[32][256];     // act strip, swizzled (16 KiB)
    __shared__ float tf_s[32][256];    // 32 KiB
    __shared__ float w_s[SEQ];
    __shared__ float red[256];
    const int r0 = b*SEQ + st*32;

    {   // stage act strip: 1024 uint4 over 256 threads
        #pragma unroll
        for (int i = 0; i < 4; ++i) {
            const int row = (tid >> 5) + i*8, c = tid & 31;
            uint4 v = *reinterpret_cast<const uint4*>(&actbf[(size_t)(r0+row)*EMB + (c<<3)]);
            *reinterpret_cast<uint4*>(&As[row][(c ^ (row&7)) << 3]) = v;
        }
    }
    // cmol = relu(seqfeat[b])·saW
    red[tid] = fmaxf(seqfeat[b*EMB + tid], 0.f) * saW[tid];
    __syncthreads();
    for (int off = 128; off; off >>= 1) {
        if (tid < off) red[tid] += red[tid + off];
        __syncthreads();
    }
    const float cb = red[0];
    __syncthreads();
    // softmax over 512 (2 per thread)
    float mk0 = mask[b*SEQ + tid], mk1 = mask[b*SEQ + 256 + tid];
    float bb = saB[0];
    float s0 = lrelu(cb + ad[b*SEQ + tid] + bb)       + (mk0 == 0.f ? NEGV : 0.f);
    float s1 = lrelu(cb + ad[b*SEQ + 256 + tid] + bb) + (mk1 == 0.f ? NEGV : 0.f);
    red[tid] = fmaxf(s0, s1); __syncthreads();
    for (int off = 128; off; off >>= 1) {
        if (tid < off) red[tid] = fmaxf(red[tid], red[tid + off]);
        __syncthreads();
    }
    float m = red[0]; __syncthreads();
    float e0v = expf(s0 - m), e1v = expf(s1 - m);
    red[tid] = e0v + e1v; __syncthreads();
    for (int off = 128; off; off >>= 1) {
        if (tid < off) red[tid] += red[tid + off];
        __syncthreads();
    }
    float inv = 1.f / red[0];
    w_s[tid]       = e0v * inv * mk0;
    w_s[tid + 256] = e1v * inv * mk1;
    __syncthreads();

    {   // tf tile: M=32 (2 sub-tiles), N=256 (4 waves x 64), K=256; B from L2
        const int wv = tid >> 6, lane = tid & 63;
        const int fr = lane & 15, grp = lane >> 4;
        f32x4 acc[2][4];
        #pragma unroll
        for (int mt = 0; mt < 2; ++mt)
            #pragma unroll
            for (int f = 0; f < 4; ++f) acc[mt][f] = (f32x4){0,0,0,0};
        #pragma unroll
        for (int kt = 0; kt < 8; ++kt) {
            short8 af[2];
            #pragma unroll
            for (int mt = 0; mt < 2; ++mt) {
                const int ar = (mt << 4) + fr;
                af[mt] = *reinterpret_cast<const short8*>(
                    &As[ar][((((kt<<2)+grp) ^ (ar&7)) << 3)]);
            }
            #pragma unroll
            for (int f = 0; f < 4; ++f) {
                const int col = (wv<<6) + (f<<4) + fr;
                short8 bv = *reinterpret_cast<const short8*>(
                    &satWbf[(size_t)col*EMB + (kt<<5) + (grp<<3)]);
                #pragma unroll
                for (int mt = 0; mt < 2; ++mt)
                    acc[mt][f] = __builtin_amdgcn_mfma_f32_16x16x32_bf16(
                        af[mt], bv, acc[mt][f], 0, 0, 0);
            }
        }
        #pragma unroll
        for (int f = 0; f < 4; ++f) {
            const int col = (wv<<6) + (f<<4) + fr;
            const float bias = satB[col];
            #pragma unroll
            for (int mt = 0; mt < 2; ++mt)
                #pragma unroll
                for (int j = 0; j < 4; ++j)
                    tf_s[(mt<<4) + (grp<<2) + j][col] = acc[mt][f][j] + bias;
        }
    }
    __syncthreads();
    {   // PV over the strip
        float acc = 0.f;
        const int s0i = st * 32;
        #pragma unroll 4
        for (int s = 0; s < 32; ++s)
            acc += w_s[s0i + s] * tf_s[s][tid];
        partial[((size_t)b*16 + st)*EMB + tid] = acc;
    }
}

// Fused tail GRU step (R11-proven). Grid 32: (b, quarter q). 512 thr, 8 waves.
template<int T0>
__global__ __launch_bounds__(512) void seqstep_kernel(
    const float* __restrict__ partial, const float* __restrict__ sfin,
    const ushort* __restrict__ sgwihbf, const float* __restrict__ sgbih,
    const ushort* __restrict__ sgwhhbf, const float* __restrict__ sgbhh,
    float* __restrict__ sgi, float* __restrict__ sfout,
    float* __restrict__ actseq)
{
    const int b = blockIdx.x >> 2, q = blockIdx.x & 3;
    const int tid = threadIdx.x, lane = tid & 63, wv = tid >> 6;
    __shared__ float xs[EMB];
    __shared__ float hs[EMB];
    __shared__ float gis[192], ghs[192];
    if (tid < EMB) {
        hs[tid] = sfin[b*EMB + tid];
        if (T0) {
            float a = 0.f;
            #pragma unroll
            for (int st = 0; st < 16; ++st)
                a += partial[((size_t)b*16 + st)*EMB + tid];
            xs[tid] = elu1(a);
        }
    }
    if (!T0) {
        for (int l = tid; l < 192; l += 512) {
            int g = (l >> 6)*EMB + (q << 6) + (l & 63);
            gis[l] = sgi[b*G3 + g];
        }
    }
    __syncthreads();
    const int nrows = T0 ? 384 : 192;
    const int rpw = nrows >> 3;
    for (int i = 0; i < rpw; ++i) {
        const int l = wv * rpw + i;
        const int iswih = T0 && (l < 192);
        const int ll = (T0 && l >= 192) ? l - 192 : l;
        const int g = (ll >> 6)*EMB + (q << 6) + (ll & 63);
        const ushort* Wm = iswih ? sgwihbf : sgwhhbf;
        ushort4 w4 = *reinterpret_cast<const ushort4*>(&Wm[(size_t)g*EMB + (lane << 2)]);
        float4 x4 = *reinterpret_cast<const float4*>(iswih ? &xs[lane << 2] : &hs[lane << 2]);
        float d = bf2f(w4.x)*x4.x + bf2f(w4.y)*x4.y + bf2f(w4.z)*x4.z + bf2f(w4.w)*x4.w;
        #pragma unroll
        for (int off = 32; off; off >>= 1) d += __shfl_xor(d, off, 64);
        if (lane == 0) {
            if (iswih) {
                d += sgbih[g];
                gis[ll] = d;
                sgi[b*G3 + g] = d;
            } else {
                ghs[ll] = d + sgbhh[g];
            }
        }
    }
    __syncthreads();
    if (tid < 64) {
        const int e = (q << 6) + tid;
        float rg = sigm(gis[tid]       + ghs[tid]);
        float z  = sigm(gis[64 + tid]  + ghs[64 + tid]);
        float n  = tanhf(gis[128 + tid] + rg*ghs[128 + tid]);
        float hv = (1.f - z)*n + z*hs[e];
        sfout[b*EMB + e]  = hv;
        actseq[b*EMB + e] = fmaxf(hv, 0.f);
    }
}

extern "C" void kernel_launch(void* const* d_in, const int* in_sizes, int n_in,
                              void* d_out, int out_size, void* d_ws, size_t ws_size,
                              hipStream_t stream) {
    (void)in_sizes; (void)n_in; (void)out_size; (void)ws_size;
    const float* amino  = (const float*)d_in[0];
    const float* mask   = (const float*)d_in[1];
    const float* embW   = (const float*)d_in[2];
    const float* embB   = (const float*)d_in[3];
    const float* nbW    = (const float*)d_in[4];
    const float* nbB    = (const float*)d_in[5];
    const float* alignW = (const float*)d_in[6];
    const float* alignB = (const float*)d_in[7];
    const float* attW   = (const float*)d_in[8];
    const float* attB   = (const float*)d_in[9];
    const float* gwih   = (const float*)d_in[10];
    const float* gwhh   = (const float*)d_in[11];
    const float* gbih   = (const float*)d_in[12];
    const float* gbhh   = (const float*)d_in[13];
    const float* saW    = (const float*)d_in[14];
    const float* saB    = (const float*)d_in[15];
    const float* satW   = (const float*)d_in[16];
    const float* satB   = (const float*)d_in[17];
    const float* sgwih  = (const float*)d_in[18];
    const float* sgbih  = (const float*)d_in[19];
    const float* sgwhh  = (const float*)d_in[20];
    const float* sgbhh  = (const float*)d_in[21];
    const int*   idx    = (const int*)d_in[22];

    char* cur = (char*)d_ws;
    auto alloc = [&](size_t bytes) -> char* {
        char* p = cur; cur += (bytes + 255) & ~(size_t)255; return p;
    };
    float* feat    = (float*)alloc((size_t)BS*EMB*4);
    float* nbase   = (float*)alloc((size_t)BS*EMB*4);
    float* cdot    = (float*)alloc(BS*4);
    float* ndot    = (float*)alloc(BS*4);   // doubles as ad after round 2
    float* seqfeat = (float*)alloc(BSZ*EMB*4);
    float* sf2     = (float*)alloc(BSZ*EMB*4);
    float* sgi     = (float*)alloc(BSZ*G3*4);
    float* partial = (float*)alloc((size_t)BSZ*16*EMB*4);
    ushort* aminobf  = (ushort*)alloc((size_t)BS*INITD*2);
    ushort* featbf   = (ushort*)alloc((size_t)BS*EMB*2);
    ushort* nbasebf  = (ushort*)alloc((size_t)BS*EMB*2);
    ushort* actbf    = (ushort*)alloc((size_t)BS*EMB*2);
    ushort* hbf      = (ushort*)alloc((size_t)BS*EMB*2);
    ushort* ctxbf    = (ushort*)alloc((size_t)BS*EMB*2);
    ushort* gibf     = (ushort*)alloc((size_t)BS*G3*2);
    ushort* ghbf     = (ushort*)alloc((size_t)BS*G3*2);
    ushort* embWbf   = (ushort*)alloc((size_t)EMB*INITD*2);
    ushort* nbWbf    = (ushort*)alloc((size_t)EMB*INITD*2);
    ushort* attWbf   = (ushort*)alloc((size_t)3*EMB*EMB*2);
    ushort* gwihbf   = (ushort*)alloc((size_t)3*G3*EMB*2);
    ushort* gwhhbf   = (ushort*)alloc((size_t)3*G3*EMB*2);
    ushort* satWbf   = (ushort*)alloc((size_t)EMB*EMB*2);
    ushort* sgwihbf  = (ushort*)alloc((size_t)G3*EMB*2);
    ushort* sgwhhbf  = (ushort*)alloc((size_t)G3*EMB*2);

    float* out    = (float*)d_out;
    float* actseq = out;               // (B,E)
    float* act    = out + BSZ*EMB;     // (B,S,E)

    convert_flat<<<2048, 256, 0, stream>>>(
        amino, aminobf, embW, embWbf, nbW, nbWbf, attW, attWbf,
        gwih, gwihbf, gwhh, gwhhbf, satW, satWbf,
        sgwih, sgwihbf, sgwhh, sgwhhbf, seqfeat);

    featnbase_kernel<<<256, 256, 0, stream>>>(
        aminobf, embWbf, embB, feat, featbf, nbWbf, nbB, nbase, nbasebf);

    dot2_kernel<<<128, 256, 0, stream>>>(feat, nbase, alignW, cdot, ndot);

    for (int d = 0; d < 3; ++d) {
        const ushort* nbrbf   = (d == 0) ? nbasebf : actbf;
        const ushort* hprevbf = (d == 0) ? featbf  : hbf;
        gagh_kernel<<<640, 256, 0, stream>>>(
            cdot, ndot, idx, nbrbf, alignB + d,
            attWbf + (size_t)d*EMB*EMB, attB + d*EMB, ctxbf,
            hprevbf, gwhhbf + (size_t)d*G3*EMB, gbhh + d*G3, ghbf);
        gi_kernel<<<384, 256, 0, stream>>>(
            ctxbf, gwihbf + (size_t)d*G3*EMB, gbih + d*G3, gibf);
        if (d < 2) {
            grudot_kernel<0><<<BS/16, 512, 0, stream>>>(
                gibf, ghbf, hprevbf, alignW + (d+1)*2*EMB, mask,
                hbf, act, actbf, cdot, ndot, seqfeat);
        } else {
            grudot_kernel<1><<<BS/16, 512, 0, stream>>>(
                gibf, ghbf, hprevbf, saW, mask,
                hbf, act, actbf, cdot, ndot, seqfeat);   // ndot <- ad
        }
    }

    seqpvtf_kernel<<<dim3(16, BSZ), 256, 0, stream>>>(
        ndot, mask, saB, saW, seqfeat, actbf, satWbf, satB, partial);
    seqstep_kernel<1><<<32, 512, 0, stream>>>(
        partial, seqfeat, sgwihbf, sgbih, sgwhhbf, sgbhh, sgi, sf2, actseq);
    seqstep_kernel<0><<<32, 512, 0, stream>>>(
        partial, sf2, sgwihbf, sgbih, sgwhhbf, sgbhh, sgi, seqfeat, actseq);
}

// Round 16
// 158.629 us; speedup vs baseline: 1.0966x; 1.0966x over previous
//
#include <hip/hip_runtime.h>
#include <math.h>

// ProGAT: B=8,S=512,NB=23,INIT=512,E=256,R=3,T=2
// R16: R14 (best=164.8us) + dot2 folded into featnbase epilogue (partial
// row-dots via shuffle + atomicAdd into pre-zeroed cdot/ndot; f32 feat/nbase
// eliminated). 13 dispatches.

#define BSZ   8
#define SEQ   512
#define NBR   23
#define EMB   256
#define INITD 512
#define BS    (BSZ*SEQ)     // 4096
#define G3    (3*EMB)       // 768
#define NEGV  -9e8f

typedef __attribute__((ext_vector_type(8))) short short8;
typedef __attribute__((ext_vector_type(4))) float f32x4;

__device__ __forceinline__ float lrelu(float x){ return x > 0.f ? x : 0.01f*x; }
__device__ __forceinline__ float elu1 (float x){ return x > 0.f ? x : (expf(x)-1.f); }
__device__ __forceinline__ float sigm (float x){ return 1.f/(1.f+expf(-x)); }
__device__ __forceinline__ float bf2f(ushort u){
    union { unsigned int i; float f; } v; v.i = ((unsigned int)u) << 16; return v.f;
}
__device__ __forceinline__ ushort f2bf(float f){
    union { float f; unsigned int i; } v; v.f = f;
    unsigned int u = v.i;
    return (ushort)((u + 0x7FFFu + ((u >> 16) & 1u)) >> 16);   // RNE
}
__device__ __forceinline__ unsigned pk2(float a, float b){
    return (unsigned)f2bf(a) | ((unsigned)f2bf(b) << 16);
}
__device__ __forceinline__ void unpack8(uint4 v, float* o) {
    o[0]=bf2f((ushort)(v.x&0xffff)); o[1]=bf2f((ushort)(v.x>>16));
    o[2]=bf2f((ushort)(v.y&0xffff)); o[3]=bf2f((ushort)(v.y>>16));
    o[4]=bf2f((ushort)(v.z&0xffff)); o[5]=bf2f((ushort)(v.z>>16));
    o[6]=bf2f((ushort)(v.w&0xffff)); o[7]=bf2f((ushort)(v.w>>16));
}

__device__ __forceinline__ void gload_lds16(const void* g, void* l) {
    __builtin_amdgcn_global_load_lds(
        (const __attribute__((address_space(1))) unsigned int*)g,
        (__attribute__((address_space(3))) unsigned int*)l,
        16, 0, 0);
}

// ---- balanced flat converter: 9 bf16 segments + zero-fill of
// seqfeat(2048f)+cdot(4096f)+ndot(4096f) = 10240 floats (contiguous in ws).
__global__ __launch_bounds__(256) void convert_flat(
    const float* __restrict__ amino, ushort* __restrict__ aminobf,
    const float* __restrict__ embW,  ushort* __restrict__ embWbf,
    const float* __restrict__ nbW,   ushort* __restrict__ nbWbf,
    const float* __restrict__ attW,  ushort* __restrict__ attWbf,
    const float* __restrict__ gwih,  ushort* __restrict__ gwihbf,
    const float* __restrict__ gwhh,  ushort* __restrict__ gwhhbf,
    const float* __restrict__ satW,  ushort* __restrict__ satWbf,
    const float* __restrict__ sgwih, ushort* __restrict__ sgwihbf,
    const float* __restrict__ sgwhh, ushort* __restrict__ sgwhhbf,
    float* __restrict__ zeroBase)
{
    const unsigned stride = gridDim.x * 256;
    for (unsigned u = blockIdx.x*256 + threadIdx.x; u < 525568u; u += stride) {
        const float* s; ushort* d; unsigned lu;
        if      (u < 262144u) { s=amino; d=aminobf; lu=u; }
        else if (u < 278528u) { s=embW;  d=embWbf;  lu=u-262144u; }
        else if (u < 294912u) { s=nbW;   d=nbWbf;   lu=u-278528u; }
        else if (u < 319488u) { s=attW;  d=attWbf;  lu=u-294912u; }
        else if (u < 393216u) { s=gwih;  d=gwihbf;  lu=u-319488u; }
        else if (u < 466944u) { s=gwhh;  d=gwhhbf;  lu=u-393216u; }
        else if (u < 475136u) { s=satW;  d=satWbf;  lu=u-466944u; }
        else if (u < 499712u) { s=sgwih; d=sgwihbf; lu=u-475136u; }
        else if (u < 524288u) { s=sgwhh; d=sgwhhbf; lu=u-499712u; }
        else {
            unsigned i = (u - 524288u) * 8;   // 1280 units -> 10240 floats
            *reinterpret_cast<float4*>(&zeroBase[i])     = make_float4(0,0,0,0);
            *reinterpret_cast<float4*>(&zeroBase[i + 4]) = make_float4(0,0,0,0);
            continue;
        }
        size_t i = (size_t)lu * 8;
        float4 a = *reinterpret_cast<const float4*>(s + i);
        float4 b = *reinterpret_cast<const float4*>(s + i + 4);
        uint4 o;
        o.x = pk2(a.x, a.y); o.y = pk2(a.z, a.w);
        o.z = pk2(b.x, b.y); o.w = pk2(b.z, b.w);
        *reinterpret_cast<uint4*>(d + i) = o;
    }
}

// ---- 128x64 MFMA GEMM; global_load_lds staging, dbuf (256 threads).
// DOTS=1: epilogue also accumulates row-dots t·dotW[col] into dotOut[row]
// (shuffle-reduce over 16 lanes + atomicAdd; dotOut must be pre-zeroed).
struct GemmLds64 { ushort A[2][128][64]; ushort B[2][64][64]; };

template<int ACT, int DOTS>
__device__ __forceinline__ void gemm64_dev(
    const ushort* __restrict__ A, const ushort* __restrict__ W,
    const float* __restrict__ bias,
    float* __restrict__ C, ushort* __restrict__ Cbf,
    const float* __restrict__ dotW, float* __restrict__ dotOut,
    int N, int K, int bx, int by, GemmLds64& L)
{
    const int tid = threadIdx.x;
    const int m0 = bx * 128, n0 = by * 64;
    const int wv = tid >> 6, lane = tid & 63;
    const int fr = lane & 15, grp = lane >> 4;
    const int kc = K >> 3;
    const int mh = wv & 1, nh = wv >> 1;
    const int lrow = lane >> 3;
    const int csrc = (lane & 7) ^ lrow;

    f32x4 acc[4][2];
    #pragma unroll
    for (int i = 0; i < 4; ++i)
        #pragma unroll
        for (int n = 0; n < 2; ++n) acc[i][n] = (f32x4){0.f,0.f,0.f,0.f};

    auto stage = [&](int c, int k0) {
        const int kch = (k0 >> 3) + csrc;
        #pragma unroll
        for (int i = 0; i < 4; ++i) {
            const int s = (wv << 2) + i;
            gload_lds16(A + ((size_t)(m0 + (s << 3) + lrow) * kc + kch) * 8,
                        &L.A[c][s << 3][0]);
        }
        #pragma unroll
        for (int i = 0; i < 2; ++i) {
            const int s = (wv << 1) + i;
            gload_lds16(W + ((size_t)(n0 + (s << 3) + lrow) * kc + kch) * 8,
                        &L.B[c][s << 3][0]);
        }
    };
    auto compute = [&](int c) {
        #pragma unroll
        for (int ks = 0; ks < 2; ++ks) {
            short8 af[4];
            #pragma unroll
            for (int i = 0; i < 4; ++i) {
                const int ar = (mh << 6) + (i << 4) + fr;
                af[i] = *reinterpret_cast<const short8*>(
                    &L.A[c][ar][(((ks << 2) + grp) ^ (ar & 7)) << 3]);
            }
            #pragma unroll
            for (int n = 0; n < 2; ++n) {
                const int br = (nh << 5) + (n << 4) + fr;
                short8 bv = *reinterpret_cast<const short8*>(
                    &L.B[c][br][(((ks << 2) + grp) ^ (br & 7)) << 3]);
                #pragma unroll
                for (int i = 0; i < 4; ++i)
                    acc[i][n] = __builtin_amdgcn_mfma_f32_16x16x32_bf16(
                        af[i], bv, acc[i][n], 0, 0, 0);
            }
        }
    };

    const int KT = K >> 6;
    stage(0, 0);
    __syncthreads();
    int cur = 0;
    for (int kt = 1; kt < KT; ++kt) {
        stage(cur ^ 1, kt << 6);
        compute(cur);
        __syncthreads();
        cur ^= 1;
    }
    compute(cur);

    float pd[4][4];
    if (DOTS) {
        #pragma unroll
        for (int i = 0; i < 4; ++i)
            #pragma unroll
            for (int j = 0; j < 4; ++j) pd[i][j] = 0.f;
    }
    #pragma unroll
    for (int i = 0; i < 4; ++i) {
        const int mrow = m0 + (mh << 6) + (i << 4) + (grp << 2);
        #pragma unroll
        for (int n = 0; n < 2; ++n) {
            const int col = n0 + (nh << 5) + (n << 4) + fr;
            const float bv = bias[col];
            const float dw = DOTS ? dotW[col] : 0.f;
            #pragma unroll
            for (int j = 0; j < 4; ++j) {
                float t = acc[i][n][j] + bv;
                if (ACT == 1) t = lrelu(t);
                size_t off = (size_t)(mrow + j) * N + col;
                if (C)   C[off] = t;
                if (Cbf) Cbf[off] = f2bf(t);
                if (DOTS) pd[i][j] += t * dw;
            }
        }
    }
    if (DOTS) {
        #pragma unroll
        for (int i = 0; i < 4; ++i)
            #pragma unroll
            for (int j = 0; j < 4; ++j) {
                float v = pd[i][j];
                v += __shfl_xor(v, 1, 64);
                v += __shfl_xor(v, 2, 64);
                v += __shfl_xor(v, 4, 64);
                v += __shfl_xor(v, 8, 64);
                if (fr == 0)
                    atomicAdd(&dotOut[m0 + (mh << 6) + (i << 4) + (grp << 2) + j], v);
            }
    }
}

// ---- fat: feat GEMM (0..127) + nbase GEMM (128..255), K=512, bf16-only out,
// with round-0 dots accumulated into cdot/ndot.
__global__ __launch_bounds__(256) void featnbase_kernel(
    const ushort* __restrict__ aminobf,
    const ushort* __restrict__ embWbf, const float* __restrict__ embB,
    ushort* __restrict__ featbf,
    const ushort* __restrict__ nbWbf, const float* __restrict__ nbB,
    ushort* __restrict__ nbasebf,
    const float* __restrict__ alignW,
    float* __restrict__ cdot, float* __restrict__ ndot)
{
    __shared__ GemmLds64 L;
    int blk = blockIdx.x;
    if (blk < 128)
        gemm64_dev<1,1>(aminobf, embWbf, embB, nullptr, featbf,
                        alignW, cdot, EMB, INITD, blk & 31, blk >> 5, L);
    else {
        blk -= 128;
        gemm64_dev<1,1>(aminobf, nbWbf, nbB, nullptr, nbasebf,
                        alignW + EMB, ndot, EMB, INITD, blk & 31, blk >> 5, L);
    }
}

// ---- D1: gather (softmax over 23 nbrs) + attend MFMA -> ctxbf (512 thr)
struct GALds { ushort ctxpre[16][256]; ushort ctx[16][256]; float wsum_s[16]; };

__global__ __launch_bounds__(512) void gatherattend_kernel(
    const float* __restrict__ cdot, const float* __restrict__ ndot,
    const int* __restrict__ idx, const ushort* __restrict__ nbr,
    const float* __restrict__ alignBd,
    const ushort* __restrict__ attWd, const float* __restrict__ attBd,
    ushort* __restrict__ ctxbf)
{
    __shared__ GALds L;
    const int tid = threadIdx.x;
    const int r0 = blockIdx.x * 16;

    {   // gather
        const int row16 = tid >> 5, sub = tid & 31;
        const int r = r0 + row16, b = r >> 9;
        float sc = -3e38f, vm = 0.f; int rn = 0;
        if (sub < NBR) {
            int j = idx[(size_t)r*NBR + sub];
            int valid = (j >= 0);
            int jj = valid ? j : j + SEQ;   // JAX wrap: f[-1] = last row
            rn = b*SEQ + jj;
            vm = (float)valid;
            sc = lrelu(cdot[r] + ndot[rn] + alignBd[0]) + (valid ? 0.f : NEGV);
        }
        float m = sc;
        #pragma unroll
        for (int off = 16; off; off >>= 1) m = fmaxf(m, __shfl_xor(m, off, 32));
        float ev = (sub < NBR) ? expf(sc - m) : 0.f;
        float s = ev;
        #pragma unroll
        for (int off = 16; off; off >>= 1) s += __shfl_xor(s, off, 32);
        float wgt = ev * vm / s;
        float ws = wgt;
        #pragma unroll
        for (int off = 16; off; off >>= 1) ws += __shfl_xor(ws, off, 32);
        float a8[8] = {};
        const int e0 = sub << 3;
        #pragma unroll
        for (int n = 0; n < NBR; ++n) {
            float wn = __shfl(wgt, n, 32);
            int   rr = __shfl(rn, n, 32);
            uint4 v = *reinterpret_cast<const uint4*>(&nbr[(size_t)rr*EMB + e0]);
            float x[8]; unpack8(v, x);
            #pragma unroll
            for (int i = 0; i < 8; ++i) a8[i] += wn * x[i];
        }
        uint4 o;
        o.x = pk2(a8[0],a8[1]); o.y = pk2(a8[2],a8[3]);
        o.z = pk2(a8[4],a8[5]); o.w = pk2(a8[6],a8[7]);
        *reinterpret_cast<uint4*>(&L.ctxpre[row16][(sub ^ (row16&7)) << 3]) = o;
        if (sub == 0) L.wsum_s[row16] = ws;
    }
    __syncthreads();

    const int wv = tid >> 6, lane = tid & 63;
    const int fr = lane & 15, grp = lane >> 4;
    {   // attend MFMA
        f32x4 acc[2] = {(f32x4){0,0,0,0},(f32x4){0,0,0,0}};
        #pragma unroll
        for (int kt = 0; kt < 8; ++kt) {
            short8 af = *reinterpret_cast<const short8*>(
                &L.ctxpre[fr][((((kt<<2)+grp) ^ (fr&7)) << 3)]);
            #pragma unroll
            for (int f = 0; f < 2; ++f) {
                const int col = (wv<<5) + (f<<4) + fr;
                short8 bv = *reinterpret_cast<const short8*>(
                    &attWd[(size_t)col*EMB + (kt<<5) + (grp<<3)]);
                acc[f] = __builtin_amdgcn_mfma_f32_16x16x32_bf16(af, bv, acc[f], 0, 0, 0);
            }
        }
        #pragma unroll
        for (int f = 0; f < 2; ++f) {
            const int col = (wv<<5) + (f<<4) + fr;
            const float bb = attBd[col];
            #pragma unroll
            for (int j = 0; j < 4; ++j) {
                const int row = (grp<<2) + j;
                L.ctx[row][col] = f2bf(elu1(acc[f][j] + L.wsum_s[row]*bb));
            }
        }
    }
    __syncthreads();
    {   // coalesced copy out
        const int row = tid >> 5, c = tid & 31;
        uint4 v = *reinterpret_cast<const uint4*>(&L.ctx[row][c << 3]);
        *reinterpret_cast<uint4*>(&ctxbf[(size_t)(r0+row)*EMB + (c << 3)]) = v;
    }
}

// ---- D2: fat gi (0..383) + gh (384..767) big-tile GEMMs
__global__ __launch_bounds__(256) void gigh_kernel(
    const ushort* __restrict__ ctxbf, const ushort* __restrict__ gwihd,
    const float* __restrict__ gbihd, ushort* __restrict__ gibf,
    const ushort* __restrict__ hprevbf, const ushort* __restrict__ gwhhd,
    const float* __restrict__ gbhhd, ushort* __restrict__ ghbf)
{
    __shared__ GemmLds64 L;
    int blk = blockIdx.x;
    if (blk < 384)
        gemm64_dev<0,0>(ctxbf, gwihd, gbihd, nullptr, gibf, nullptr, nullptr,
                        G3, EMB, blk & 31, blk >> 5, L);
    else {
        blk -= 384;
        gemm64_dev<0,0>(hprevbf, gwhhd, gbhhd, nullptr, ghbf, nullptr, nullptr,
                        G3, EMB, blk & 31, blk >> 5, L);
    }
}

// ---- D3: GRU (bf16 state) + next-round dot2 (or seq ad if LAST).
// LAST: f32 act out + atomic seqfeat accumulation.
template<int LAST>
__global__ __launch_bounds__(512) void grudot_kernel(
    const ushort* __restrict__ gibf, const ushort* __restrict__ ghbf,
    const ushort* __restrict__ hprevbf, const float* __restrict__ nextW,
    const float* __restrict__ mask,
    ushort* __restrict__ hbf, float* __restrict__ actout,
    ushort* __restrict__ actbf,
    float* __restrict__ cdotO, float* __restrict__ ndotO,
    float* __restrict__ seqfeatA)
{
    __shared__ float sred[16][256];
    const int tid = threadIdx.x;
    const int row = tid >> 5, sub = tid & 31;
    const int e0 = sub << 3;
    const size_t r = (size_t)blockIdx.x * 16 + row;
    const size_t gb = r*G3;
    uint4 giA = *reinterpret_cast<const uint4*>(&gibf[gb + e0]);
    uint4 giB = *reinterpret_cast<const uint4*>(&gibf[gb + 256 + e0]);
    uint4 giC = *reinterpret_cast<const uint4*>(&gibf[gb + 512 + e0]);
    uint4 ghA = *reinterpret_cast<const uint4*>(&ghbf[gb + e0]);
    uint4 ghB = *reinterpret_cast<const uint4*>(&ghbf[gb + 256 + e0]);
    uint4 ghC = *reinterpret_cast<const uint4*>(&ghbf[gb + 512 + e0]);
    uint4 hpv = *reinterpret_cast<const uint4*>(&hprevbf[r*EMB + e0]);
    float ir_[8], iz_[8], in_[8], hr_[8], hz_[8], hn_[8], hp_[8];
    unpack8(giA, ir_); unpack8(giB, iz_); unpack8(giC, in_);
    unpack8(ghA, hr_); unpack8(ghB, hz_); unpack8(ghC, hn_);
    unpack8(hpv, hp_);
    float hv8[8], av8[8];
    #pragma unroll
    for (int i = 0; i < 8; ++i) {
        float rg = sigm(ir_[i] + hr_[i]);
        float z  = sigm(iz_[i] + hz_[i]);
        float n  = tanhf(in_[i] + rg*hn_[i]);
        hv8[i] = (1.f - z)*n + z*hp_[i];
        av8[i] = fmaxf(hv8[i], 0.f);
    }
    if (LAST) {
        *reinterpret_cast<float4*>(&actout[r*EMB + e0])     = make_float4(av8[0],av8[1],av8[2],av8[3]);
        *reinterpret_cast<float4*>(&actout[r*EMB + e0 + 4]) = make_float4(av8[4],av8[5],av8[6],av8[7]);
    }
    uint4 hb, ab;
    hb.x = pk2(hv8[0],hv8[1]); hb.y = pk2(hv8[2],hv8[3]);
    hb.z = pk2(hv8[4],hv8[5]); hb.w = pk2(hv8[6],hv8[7]);
    ab.x = pk2(av8[0],av8[1]); ab.y = pk2(av8[2],av8[3]);
    ab.z = pk2(av8[4],av8[5]); ab.w = pk2(av8[6],av8[7]);
    *reinterpret_cast<uint4*>(&hbf[r*EMB + e0])   = hb;
    *reinterpret_cast<uint4*>(&actbf[r*EMB + e0]) = ab;
    float pc = 0.f, pn = 0.f;
    float4 w1a = *reinterpret_cast<const float4*>(&nextW[EMB + e0]);
    float4 w1b = *reinterpret_cast<const float4*>(&nextW[EMB + e0 + 4]);
    pn = av8[0]*w1a.x + av8[1]*w1a.y + av8[2]*w1a.z + av8[3]*w1a.w
       + av8[4]*w1b.x + av8[5]*w1b.y + av8[6]*w1b.z + av8[7]*w1b.w;
    if (!LAST) {
        float4 w0a = *reinterpret_cast<const float4*>(&nextW[e0]);
        float4 w0b = *reinterpret_cast<const float4*>(&nextW[e0 + 4]);
        pc = av8[0]*w0a.x + av8[1]*w0a.y + av8[2]*w0a.z + av8[3]*w0a.w
           + av8[4]*w0b.x + av8[5]*w0b.y + av8[6]*w0b.z + av8[7]*w0b.w;
    }
    #pragma unroll
    for (int off = 16; off; off >>= 1) {
        pn += __shfl_xor(pn, off, 32);
        if (!LAST) pc += __shfl_xor(pc, off, 32);
    }
    if (sub == 0) {
        if (!LAST) cdotO[r] = pc;
        ndotO[r] = pn;
    }
    if (LAST) {
        const float mk = mask[r];
        #pragma unroll
        for (int i = 0; i < 8; ++i) sred[row][e0 + i] = av8[i] * mk;
        __syncthreads();
        if (tid < 256) {
            float s = 0.f;
            #pragma unroll
            for (int rr = 0; rr < 16; ++rr) s += sred[rr][tid];
            atomicAdd(&seqfeatA[(blockIdx.x >> 5)*EMB + tid], s);
        }
    }
}

// ---- tail: tf GEMM only (128 blocks)
__global__ __launch_bounds__(256) void seqpre_kernel(
    const ushort* __restrict__ actbf, const ushort* __restrict__ satWbf,
    const float* __restrict__ satB, float* __restrict__ tf)
{
    __shared__ GemmLds64 L;
    gemm64_dev<0,0>(actbf, satWbf, satB, tf, nullptr, nullptr, nullptr,
                    EMB, EMB, blockIdx.x & 31, blockIdx.x >> 5, L);
}

// ---- seqpv2: cmol (inline, redundant per block) + softmax + 32-s PV strip.
__global__ __launch_bounds__(256) void seqpv2_kernel(
    const float* __restrict__ ad, const float* __restrict__ mask,
    const float* __restrict__ saB, const float* __restrict__ saW,
    const float* __restrict__ seqfeat, const float* __restrict__ tf,
    float* __restrict__ partial)
{
    const int st = blockIdx.x, b = blockIdx.y;
    const int tid = threadIdx.x;
    __shared__ float w_s[SEQ];
    __shared__ float red[256];
    red[tid] = fmaxf(seqfeat[b*EMB + tid], 0.f) * saW[tid];
    __syncthreads();
    for (int off = 128; off; off >>= 1) {
        if (tid < off) red[tid] += red[tid + off];
        __syncthreads();
    }
    const float cb = red[0];
    __syncthreads();
    float mk0 = mask[b*SEQ + tid], mk1 = mask[b*SEQ + 256 + tid];
    float bb = saB[0];
    float s0 = lrelu(cb + ad[b*SEQ + tid] + bb)       + (mk0 == 0.f ? NEGV : 0.f);
    float s1 = lrelu(cb + ad[b*SEQ + 256 + tid] + bb) + (mk1 == 0.f ? NEGV : 0.f);
    red[tid] = fmaxf(s0, s1); __syncthreads();
    for (int off = 128; off; off >>= 1) {
        if (tid < off) red[tid] = fmaxf(red[tid], red[tid + off]);
        __syncthreads();
    }
    float m = red[0]; __syncthreads();
    float e0 = expf(s0 - m), e1 = expf(s1 - m);
    red[tid] = e0 + e1; __syncthreads();
    for (int off = 128; off; off >>= 1) {
        if (tid < off) red[tid] += red[tid + off];
        __syncthreads();
    }
    float inv = 1.f / red[0];
    w_s[tid]       = e0 * inv * mk0;
    w_s[tid + 256] = e1 * inv * mk1;
    __syncthreads();
    float acc = 0.f;
    const int s0i = st * 32;
    #pragma unroll 4
    for (int s = s0i; s < s0i + 32; ++s)
        acc += w_s[s] * tf[((size_t)b*SEQ + s)*EMB + tid];
    partial[((size_t)b*16 + st)*EMB + tid] = acc;
}

// Fused tail GRU step. Grid 32: (b, quarter q). 512 thr, 8 waves.
template<int T0>
__global__ __launch_bounds__(512) void seqstep_kernel(
    const float* __restrict__ partial, const float* __restrict__ sfin,
    const ushort* __restrict__ sgwihbf, const float* __restrict__ sgbih,
    const ushort* __restrict__ sgwhhbf, const float* __restrict__ sgbhh,
    float* __restrict__ sgi, float* __restrict__ sfout,
    float* __restrict__ actseq)
{
    const int b = blockIdx.x >> 2, q = blockIdx.x & 3;
    const int tid = threadIdx.x, lane = tid & 63, wv = tid >> 6;
    __shared__ float xs[EMB];
    __shared__ float hs[EMB];
    __shared__ float gis[192], ghs[192];
    if (tid < EMB) {
        hs[tid] = sfin[b*EMB + tid];
        if (T0) {
            float a = 0.f;
            #pragma unroll
            for (int st = 0; st < 16; ++st)
                a += partial[((size_t)b*16 + st)*EMB + tid];
            xs[tid] = elu1(a);
        }
    }
    if (!T0) {
        for (int l = tid; l < 192; l += 512) {
            int g = (l >> 6)*EMB + (q << 6) + (l & 63);
            gis[l] = sgi[b*G3 + g];
        }
    }
    __syncthreads();
    const int nrows = T0 ? 384 : 192;
    const int rpw = nrows >> 3;
    for (int i = 0; i < rpw; ++i) {
        const int l = wv * rpw + i;
        const int iswih = T0 && (l < 192);
        const int ll = (T0 && l >= 192) ? l - 192 : l;
        const int g = (ll >> 6)*EMB + (q << 6) + (ll & 63);
        const ushort* Wm = iswih ? sgwihbf : sgwhhbf;
        ushort4 w4 = *reinterpret_cast<const ushort4*>(&Wm[(size_t)g*EMB + (lane << 2)]);
        float4 x4 = *reinterpret_cast<const float4*>(iswih ? &xs[lane << 2] : &hs[lane << 2]);
        float d = bf2f(w4.x)*x4.x + bf2f(w4.y)*x4.y + bf2f(w4.z)*x4.z + bf2f(w4.w)*x4.w;
        #pragma unroll
        for (int off = 32; off; off >>= 1) d += __shfl_xor(d, off, 64);
        if (lane == 0) {
            if (iswih) {
                d += sgbih[g];
                gis[ll] = d;
                sgi[b*G3 + g] = d;
            } else {
                ghs[ll] = d + sgbhh[g];
            }
        }
    }
    __syncthreads();
    if (tid < 64) {
        const int e = (q << 6) + tid;
        float rg = sigm(gis[tid]       + ghs[tid]);
        float z  = sigm(gis[64 + tid]  + ghs[64 + tid]);
        float n  = tanhf(gis[128 + tid] + rg*ghs[128 + tid]);
        float hv = (1.f - z)*n + z*hs[e];
        sfout[b*EMB + e]  = hv;
        actseq[b*EMB + e] = fmaxf(hv, 0.f);
    }
}

extern "C" void kernel_launch(void* const* d_in, const int* in_sizes, int n_in,
                              void* d_out, int out_size, void* d_ws, size_t ws_size,
                              hipStream_t stream) {
    (void)in_sizes; (void)n_in; (void)out_size; (void)ws_size;
    const float* amino  = (const float*)d_in[0];
    const float* mask   = (const float*)d_in[1];
    const float* embW   = (const float*)d_in[2];
    const float* embB   = (const float*)d_in[3];
    const float* nbW    = (const float*)d_in[4];
    const float* nbB    = (const float*)d_in[5];
    const float* alignW = (const float*)d_in[6];
    const float* alignB = (const float*)d_in[7];
    const float* attW   = (const float*)d_in[8];
    const float* attB   = (const float*)d_in[9];
    const float* gwih   = (const float*)d_in[10];
    const float* gwhh   = (const float*)d_in[11];
    const float* gbih   = (const float*)d_in[12];
    const float* gbhh   = (const float*)d_in[13];
    const float* saW    = (const float*)d_in[14];
    const float* saB    = (const float*)d_in[15];
    const float* satW   = (const float*)d_in[16];
    const float* satB   = (const float*)d_in[17];
    const float* sgwih  = (const float*)d_in[18];
    const float* sgbih  = (const float*)d_in[19];
    const float* sgwhh  = (const float*)d_in[20];
    const float* sgbhh  = (const float*)d_in[21];
    const int*   idx    = (const int*)d_in[22];

    char* cur = (char*)d_ws;
    auto alloc = [&](size_t bytes) -> char* {
        char* p = cur; cur += (bytes + 255) & ~(size_t)255; return p;
    };
    // seqfeat, cdot, ndot contiguous (zeroed as one 40KB range by convert_flat)
    float* seqfeat = (float*)alloc(BSZ*EMB*4);   // 8192B
    float* cdot    = (float*)alloc(BS*4);        // 16384B
    float* ndot    = (float*)alloc(BS*4);        // 16384B (doubles as ad)
    float* tf      = (float*)alloc((size_t)BS*EMB*4);
    float* sf2     = (float*)alloc(BSZ*EMB*4);
    float* sgi     = (float*)alloc(BSZ*G3*4);
    float* partial = (float*)alloc((size_t)BSZ*16*EMB*4);
    ushort* aminobf  = (ushort*)alloc((size_t)BS*INITD*2);
    ushort* featbf   = (ushort*)alloc((size_t)BS*EMB*2);
    ushort* nbasebf  = (ushort*)alloc((size_t)BS*EMB*2);
    ushort* actbf    = (ushort*)alloc((size_t)BS*EMB*2);
    ushort* hbf      = (ushort*)alloc((size_t)BS*EMB*2);
    ushort* ctxbf    = (ushort*)alloc((size_t)BS*EMB*2);
    ushort* gibf     = (ushort*)alloc((size_t)BS*G3*2);
    ushort* ghbf     = (ushort*)alloc((size_t)BS*G3*2);
    ushort* embWbf   = (ushort*)alloc((size_t)EMB*INITD*2);
    ushort* nbWbf    = (ushort*)alloc((size_t)EMB*INITD*2);
    ushort* attWbf   = (ushort*)alloc((size_t)3*EMB*EMB*2);
    ushort* gwihbf   = (ushort*)alloc((size_t)3*G3*EMB*2);
    ushort* gwhhbf   = (ushort*)alloc((size_t)3*G3*EMB*2);
    ushort* satWbf   = (ushort*)alloc((size_t)EMB*EMB*2);
    ushort* sgwihbf  = (ushort*)alloc((size_t)G3*EMB*2);
    ushort* sgwhhbf  = (ushort*)alloc((size_t)G3*EMB*2);

    float* out    = (float*)d_out;
    float* actseq = out;               // (B,E)
    float* act    = out + BSZ*EMB;     // (B,S,E)

    convert_flat<<<2048, 256, 0, stream>>>(
        amino, aminobf, embW, embWbf, nbW, nbWbf, attW, attWbf,
        gwih, gwihbf, gwhh, gwhhbf, satW, satWbf,
        sgwih, sgwihbf, sgwhh, sgwhhbf, seqfeat);

    featnbase_kernel<<<256, 256, 0, stream>>>(
        aminobf, embWbf, embB, featbf, nbWbf, nbB, nbasebf,
        alignW, cdot, ndot);

    for (int d = 0; d < 3; ++d) {
        const ushort* nbrbf   = (d == 0) ? nbasebf : actbf;
        const ushort* hprevbf = (d == 0) ? featbf  : hbf;
        gatherattend_kernel<<<BS/16, 512, 0, stream>>>(
            cdot, ndot, idx, nbrbf, alignB + d,
            attWbf + (size_t)d*EMB*EMB, attB + d*EMB, ctxbf);
        gigh_kernel<<<768, 256, 0, stream>>>(
            ctxbf, gwihbf + (size_t)d*G3*EMB, gbih + d*G3, gibf,
            hprevbf, gwhhbf + (size_t)d*G3*EMB, gbhh + d*G3, ghbf);
        if (d < 2) {
            grudot_kernel<0><<<BS/16, 512, 0, stream>>>(
                gibf, ghbf, hprevbf, alignW + (d+1)*2*EMB, mask,
                hbf, act, actbf, cdot, ndot, seqfeat);
        } else {
            grudot_kernel<1><<<BS/16, 512, 0, stream>>>(
                gibf, ghbf, hprevbf, saW, mask,
                hbf, act, actbf, cdot, ndot, seqfeat);   // ndot <- ad
        }
    }

    seqpre_kernel<<<128, 256, 0, stream>>>(actbf, satWbf, satB, tf);
    seqpv2_kernel<<<dim3(16, BSZ), 256, 0, stream>>>(
        ndot, mask, saB, saW, seqfeat, tf, partial);
    seqstep_kernel<1><<<32, 512, 0, stream>>>(
        partial, seqfeat, sgwihbf, sgbih, sgwhhbf, sgbhh, sgi, sf2, actseq);
    seqstep_kernel<0><<<32, 512, 0, stream>>>(
        partial, sf2, sgwihbf, sgbih, sgwhhbf, sgbhh, sgi, seqfeat, actseq);
}

// Round 17
// 156.898 us; speedup vs baseline: 1.1087x; 1.0110x over previous
//
#include <hip/hip_runtime.h>
#include <math.h>

// ProGAT: B=8,S=512,NB=23,INIT=512,E=256,R=3,T=2
// R17: R16 (158.6us) + (a) convert split: core (amino/embW/nbW/zero) first,
// remaining 6 weight segments hidden inside featnbase dispatch; (b) tail
// seqpre folded into seqpvtf (per-strip tf tile via MFMA). 12 dispatches.

#define BSZ   8
#define SEQ   512
#define NBR   23
#define EMB   256
#define INITD 512
#define BS    (BSZ*SEQ)     // 4096
#define G3    (3*EMB)       // 768
#define NEGV  -9e8f

typedef __attribute__((ext_vector_type(8))) short short8;
typedef __attribute__((ext_vector_type(4))) float f32x4;

__device__ __forceinline__ float lrelu(float x){ return x > 0.f ? x : 0.01f*x; }
__device__ __forceinline__ float elu1 (float x){ return x > 0.f ? x : (expf(x)-1.f); }
__device__ __forceinline__ float sigm (float x){ return 1.f/(1.f+expf(-x)); }
__device__ __forceinline__ float bf2f(ushort u){
    union { unsigned int i; float f; } v; v.i = ((unsigned int)u) << 16; return v.f;
}
__device__ __forceinline__ ushort f2bf(float f){
    union { float f; unsigned int i; } v; v.f = f;
    unsigned int u = v.i;
    return (ushort)((u + 0x7FFFu + ((u >> 16) & 1u)) >> 16);   // RNE
}
__device__ __forceinline__ unsigned pk2(float a, float b){
    return (unsigned)f2bf(a) | ((unsigned)f2bf(b) << 16);
}
__device__ __forceinline__ void unpack8(uint4 v, float* o) {
    o[0]=bf2f((ushort)(v.x&0xffff)); o[1]=bf2f((ushort)(v.x>>16));
    o[2]=bf2f((ushort)(v.y&0xffff)); o[3]=bf2f((ushort)(v.y>>16));
    o[4]=bf2f((ushort)(v.z&0xffff)); o[5]=bf2f((ushort)(v.z>>16));
    o[6]=bf2f((ushort)(v.w&0xffff)); o[7]=bf2f((ushort)(v.w>>16));
}

__device__ __forceinline__ void gload_lds16(const void* g, void* l) {
    __builtin_amdgcn_global_load_lds(
        (const __attribute__((address_space(1))) unsigned int*)g,
        (__attribute__((address_space(3))) unsigned int*)l,
        16, 0, 0);
}

__device__ __forceinline__ void conv_unit(const float* s, ushort* d, size_t i) {
    float4 a = *reinterpret_cast<const float4*>(s + i);
    float4 b = *reinterpret_cast<const float4*>(s + i + 4);
    uint4 o;
    o.x = pk2(a.x, a.y); o.y = pk2(a.z, a.w);
    o.z = pk2(b.x, b.y); o.w = pk2(b.z, b.w);
    *reinterpret_cast<uint4*>(d + i) = o;
}

// ---- convert_core: amino + embW + nbW + zero-fill(seqfeat,cdot,ndot=10240f)
__global__ __launch_bounds__(256) void convert_core(
    const float* __restrict__ amino, ushort* __restrict__ aminobf,
    const float* __restrict__ embW,  ushort* __restrict__ embWbf,
    const float* __restrict__ nbW,   ushort* __restrict__ nbWbf,
    float* __restrict__ zeroBase)
{
    const unsigned stride = gridDim.x * 256;
    for (unsigned u = blockIdx.x*256 + threadIdx.x; u < 296192u; u += stride) {
        if      (u < 262144u) conv_unit(amino, aminobf, (size_t)u*8);
        else if (u < 278528u) conv_unit(embW,  embWbf,  (size_t)(u-262144u)*8);
        else if (u < 294912u) conv_unit(nbW,   nbWbf,   (size_t)(u-278528u)*8);
        else {
            unsigned i = (u - 294912u) * 8;   // 1280 units -> 10240 floats
            *reinterpret_cast<float4*>(&zeroBase[i])     = make_float4(0,0,0,0);
            *reinterpret_cast<float4*>(&zeroBase[i + 4]) = make_float4(0,0,0,0);
        }
    }
}

// ---- convert_rest: 6 weight segments (229376 units), grid-strided
__device__ __forceinline__ void convert_rest(
    int blk, int nblk,
    const float* attW, ushort* attWbf,
    const float* gwih, ushort* gwihbf,
    const float* gwhh, ushort* gwhhbf,
    const float* satW, ushort* satWbf,
    const float* sgwih, ushort* sgwihbf,
    const float* sgwhh, ushort* sgwhhbf)
{
    const unsigned stride = nblk * 256;
    for (unsigned u = blk*256 + threadIdx.x; u < 229376u; u += stride) {
        if      (u < 24576u)  conv_unit(attW,  attWbf,  (size_t)u*8);
        else if (u < 98304u)  conv_unit(gwih,  gwihbf,  (size_t)(u-24576u)*8);
        else if (u < 172032u) conv_unit(gwhh,  gwhhbf,  (size_t)(u-98304u)*8);
        else if (u < 180224u) conv_unit(satW,  satWbf,  (size_t)(u-172032u)*8);
        else if (u < 204800u) conv_unit(sgwih, sgwihbf, (size_t)(u-180224u)*8);
        else                  conv_unit(sgwhh, sgwhhbf, (size_t)(u-204800u)*8);
    }
}

// ---- 128x64 MFMA GEMM; global_load_lds staging, dbuf (256 threads).
// DOTS=1: epilogue accumulates row-dots into pre-zeroed dotOut via atomics.
struct GemmLds64 { ushort A[2][128][64]; ushort B[2][64][64]; };

template<int ACT, int DOTS>
__device__ __forceinline__ void gemm64_dev(
    const ushort* __restrict__ A, const ushort* __restrict__ W,
    const float* __restrict__ bias,
    float* __restrict__ C, ushort* __restrict__ Cbf,
    const float* __restrict__ dotW, float* __restrict__ dotOut,
    int N, int K, int bx, int by, GemmLds64& L)
{
    const int tid = threadIdx.x;
    const int m0 = bx * 128, n0 = by * 64;
    const int wv = tid >> 6, lane = tid & 63;
    const int fr = lane & 15, grp = lane >> 4;
    const int kc = K >> 3;
    const int mh = wv & 1, nh = wv >> 1;
    const int lrow = lane >> 3;
    const int csrc = (lane & 7) ^ lrow;

    f32x4 acc[4][2];
    #pragma unroll
    for (int i = 0; i < 4; ++i)
        #pragma unroll
        for (int n = 0; n < 2; ++n) acc[i][n] = (f32x4){0.f,0.f,0.f,0.f};

    auto stage = [&](int c, int k0) {
        const int kch = (k0 >> 3) + csrc;
        #pragma unroll
        for (int i = 0; i < 4; ++i) {
            const int s = (wv << 2) + i;
            gload_lds16(A + ((size_t)(m0 + (s << 3) + lrow) * kc + kch) * 8,
                        &L.A[c][s << 3][0]);
        }
        #pragma unroll
        for (int i = 0; i < 2; ++i) {
            const int s = (wv << 1) + i;
            gload_lds16(W + ((size_t)(n0 + (s << 3) + lrow) * kc + kch) * 8,
                        &L.B[c][s << 3][0]);
        }
    };
    auto compute = [&](int c) {
        #pragma unroll
        for (int ks = 0; ks < 2; ++ks) {
            short8 af[4];
            #pragma unroll
            for (int i = 0; i < 4; ++i) {
                const int ar = (mh << 6) + (i << 4) + fr;
                af[i] = *reinterpret_cast<const short8*>(
                    &L.A[c][ar][(((ks << 2) + grp) ^ (ar & 7)) << 3]);
            }
            #pragma unroll
            for (int n = 0; n < 2; ++n) {
                const int br = (nh << 5) + (n << 4) + fr;
                short8 bv = *reinterpret_cast<const short8*>(
                    &L.B[c][br][(((ks << 2) + grp) ^ (br & 7)) << 3]);
                #pragma unroll
                for (int i = 0; i < 4; ++i)
                    acc[i][n] = __builtin_amdgcn_mfma_f32_16x16x32_bf16(
                        af[i], bv, acc[i][n], 0, 0, 0);
            }
        }
    };

    const int KT = K >> 6;
    stage(0, 0);
    __syncthreads();
    int cur = 0;
    for (int kt = 1; kt < KT; ++kt) {
        stage(cur ^ 1, kt << 6);
        compute(cur);
        __syncthreads();
        cur ^= 1;
    }
    compute(cur);

    float pd[4][4];
    if (DOTS) {
        #pragma unroll
        for (int i = 0; i < 4; ++i)
            #pragma unroll
            for (int j = 0; j < 4; ++j) pd[i][j] = 0.f;
    }
    #pragma unroll
    for (int i = 0; i < 4; ++i) {
        const int mrow = m0 + (mh << 6) + (i << 4) + (grp << 2);
        #pragma unroll
        for (int n = 0; n < 2; ++n) {
            const int col = n0 + (nh << 5) + (n << 4) + fr;
            const float bv = bias[col];
            const float dw = DOTS ? dotW[col] : 0.f;
            #pragma unroll
            for (int j = 0; j < 4; ++j) {
                float t = acc[i][n][j] + bv;
                if (ACT == 1) t = lrelu(t);
                size_t off = (size_t)(mrow + j) * N + col;
                if (C)   C[off] = t;
                if (Cbf) Cbf[off] = f2bf(t);
                if (DOTS) pd[i][j] += t * dw;
            }
        }
    }
    if (DOTS) {
        #pragma unroll
        for (int i = 0; i < 4; ++i)
            #pragma unroll
            for (int j = 0; j < 4; ++j) {
                float v = pd[i][j];
                v += __shfl_xor(v, 1, 64);
                v += __shfl_xor(v, 2, 64);
                v += __shfl_xor(v, 4, 64);
                v += __shfl_xor(v, 8, 64);
                if (fr == 0)
                    atomicAdd(&dotOut[m0 + (mh << 6) + (i << 4) + (grp << 2) + j], v);
            }
    }
}

// ---- fat: feat GEMM (0..127) + nbase GEMM (128..255) + convert_rest (256..383)
__global__ __launch_bounds__(256) void featnbase_kernel(
    const ushort* __restrict__ aminobf,
    const ushort* __restrict__ embWbf, const float* __restrict__ embB,
    ushort* __restrict__ featbf,
    const ushort* __restrict__ nbWbf, const float* __restrict__ nbB,
    ushort* __restrict__ nbasebf,
    const float* __restrict__ alignW,
    float* __restrict__ cdot, float* __restrict__ ndot,
    const float* attW, ushort* attWbf,
    const float* gwih, ushort* gwihbf,
    const float* gwhh, ushort* gwhhbf,
    const float* satW, ushort* satWbf,
    const float* sgwih, ushort* sgwihbf,
    const float* sgwhh, ushort* sgwhhbf)
{
    __shared__ GemmLds64 L;
    int blk = blockIdx.x;
    if (blk < 128)
        gemm64_dev<1,1>(aminobf, embWbf, embB, nullptr, featbf,
                        alignW, cdot, EMB, INITD, blk & 31, blk >> 5, L);
    else if (blk < 256) {
        blk -= 128;
        gemm64_dev<1,1>(aminobf, nbWbf, nbB, nullptr, nbasebf,
                        alignW + EMB, ndot, EMB, INITD, blk & 31, blk >> 5, L);
    } else {
        convert_rest(blk - 256, 128, attW, attWbf, gwih, gwihbf,
                     gwhh, gwhhbf, satW, satWbf, sgwih, sgwihbf, sgwhh, sgwhhbf);
    }
}

// ---- D1: gather (softmax over 23 nbrs) + attend MFMA -> ctxbf (512 thr)
struct GALds { ushort ctxpre[16][256]; ushort ctx[16][256]; float wsum_s[16]; };

__global__ __launch_bounds__(512) void gatherattend_kernel(
    const float* __restrict__ cdot, const float* __restrict__ ndot,
    const int* __restrict__ idx, const ushort* __restrict__ nbr,
    const float* __restrict__ alignBd,
    const ushort* __restrict__ attWd, const float* __restrict__ attBd,
    ushort* __restrict__ ctxbf)
{
    __shared__ GALds L;
    const int tid = threadIdx.x;
    const int r0 = blockIdx.x * 16;

    {   // gather
        const int row16 = tid >> 5, sub = tid & 31;
        const int r = r0 + row16, b = r >> 9;
        float sc = -3e38f, vm = 0.f; int rn = 0;
        if (sub < NBR) {
            int j = idx[(size_t)r*NBR + sub];
            int valid = (j >= 0);
            int jj = valid ? j : j + SEQ;   // JAX wrap: f[-1] = last row
            rn = b*SEQ + jj;
            vm = (float)valid;
            sc = lrelu(cdot[r] + ndot[rn] + alignBd[0]) + (valid ? 0.f : NEGV);
        }
        float m = sc;
        #pragma unroll
        for (int off = 16; off; off >>= 1) m = fmaxf(m, __shfl_xor(m, off, 32));
        float ev = (sub < NBR) ? expf(sc - m) : 0.f;
        float s = ev;
        #pragma unroll
        for (int off = 16; off; off >>= 1) s += __shfl_xor(s, off, 32);
        float wgt = ev * vm / s;
        float ws = wgt;
        #pragma unroll
        for (int off = 16; off; off >>= 1) ws += __shfl_xor(ws, off, 32);
        float a8[8] = {};
        const int e0 = sub << 3;
        #pragma unroll
        for (int n = 0; n < NBR; ++n) {
            float wn = __shfl(wgt, n, 32);
            int   rr = __shfl(rn, n, 32);
            uint4 v = *reinterpret_cast<const uint4*>(&nbr[(size_t)rr*EMB + e0]);
            float x[8]; unpack8(v, x);
            #pragma unroll
            for (int i = 0; i < 8; ++i) a8[i] += wn * x[i];
        }
        uint4 o;
        o.x = pk2(a8[0],a8[1]); o.y = pk2(a8[2],a8[3]);
        o.z = pk2(a8[4],a8[5]); o.w = pk2(a8[6],a8[7]);
        *reinterpret_cast<uint4*>(&L.ctxpre[row16][(sub ^ (row16&7)) << 3]) = o;
        if (sub == 0) L.wsum_s[row16] = ws;
    }
    __syncthreads();

    const int wv = tid >> 6, lane = tid & 63;
    const int fr = lane & 15, grp = lane >> 4;
    {   // attend MFMA
        f32x4 acc[2] = {(f32x4){0,0,0,0},(f32x4){0,0,0,0}};
        #pragma unroll
        for (int kt = 0; kt < 8; ++kt) {
            short8 af = *reinterpret_cast<const short8*>(
                &L.ctxpre[fr][((((kt<<2)+grp) ^ (fr&7)) << 3)]);
            #pragma unroll
            for (int f = 0; f < 2; ++f) {
                const int col = (wv<<5) + (f<<4) + fr;
                short8 bv = *reinterpret_cast<const short8*>(
                    &attWd[(size_t)col*EMB + (kt<<5) + (grp<<3)]);
                acc[f] = __builtin_amdgcn_mfma_f32_16x16x32_bf16(af, bv, acc[f], 0, 0, 0);
            }
        }
        #pragma unroll
        for (int f = 0; f < 2; ++f) {
            const int col = (wv<<5) + (f<<4) + fr;
            const float bb = attBd[col];
            #pragma unroll
            for (int j = 0; j < 4; ++j) {
                const int row = (grp<<2) + j;
                L.ctx[row][col] = f2bf(elu1(acc[f][j] + L.wsum_s[row]*bb));
            }
        }
    }
    __syncthreads();
    {   // coalesced copy out
        const int row = tid >> 5, c = tid & 31;
        uint4 v = *reinterpret_cast<const uint4*>(&L.ctx[row][c << 3]);
        *reinterpret_cast<uint4*>(&ctxbf[(size_t)(r0+row)*EMB + (c << 3)]) = v;
    }
}

// ---- D2: fat gi (0..383) + gh (384..767) big-tile GEMMs
__global__ __launch_bounds__(256) void gigh_kernel(
    const ushort* __restrict__ ctxbf, const ushort* __restrict__ gwihd,
    const float* __restrict__ gbihd, ushort* __restrict__ gibf,
    const ushort* __restrict__ hprevbf, const ushort* __restrict__ gwhhd,
    const float* __restrict__ gbhhd, ushort* __restrict__ ghbf)
{
    __shared__ GemmLds64 L;
    int blk = blockIdx.x;
    if (blk < 384)
        gemm64_dev<0,0>(ctxbf, gwihd, gbihd, nullptr, gibf, nullptr, nullptr,
                        G3, EMB, blk & 31, blk >> 5, L);
    else {
        blk -= 384;
        gemm64_dev<0,0>(hprevbf, gwhhd, gbhhd, nullptr, ghbf, nullptr, nullptr,
                        G3, EMB, blk & 31, blk >> 5, L);
    }
}

// ---- D3: GRU (bf16 state) + next-round dot2 (or seq ad if LAST).
template<int LAST>
__global__ __launch_bounds__(512) void grudot_kernel(
    const ushort* __restrict__ gibf, const ushort* __restrict__ ghbf,
    const ushort* __restrict__ hprevbf, const float* __restrict__ nextW,
    const float* __restrict__ mask,
    ushort* __restrict__ hbf, float* __restrict__ actout,
    ushort* __restrict__ actbf,
    float* __restrict__ cdotO, float* __restrict__ ndotO,
    float* __restrict__ seqfeatA)
{
    __shared__ float sred[16][256];
    const int tid = threadIdx.x;
    const int row = tid >> 5, sub = tid & 31;
    const int e0 = sub << 3;
    const size_t r = (size_t)blockIdx.x * 16 + row;
    const size_t gb = r*G3;
    uint4 giA = *reinterpret_cast<const uint4*>(&gibf[gb + e0]);
    uint4 giB = *reinterpret_cast<const uint4*>(&gibf[gb + 256 + e0]);
    uint4 giC = *reinterpret_cast<const uint4*>(&gibf[gb + 512 + e0]);
    uint4 ghA = *reinterpret_cast<const uint4*>(&ghbf[gb + e0]);
    uint4 ghB = *reinterpret_cast<const uint4*>(&ghbf[gb + 256 + e0]);
    uint4 ghC = *reinterpret_cast<const uint4*>(&ghbf[gb + 512 + e0]);
    uint4 hpv = *reinterpret_cast<const uint4*>(&hprevbf[r*EMB + e0]);
    float ir_[8], iz_[8], in_[8], hr_[8], hz_[8], hn_[8], hp_[8];
    unpack8(giA, ir_); unpack8(giB, iz_); unpack8(giC, in_);
    unpack8(ghA, hr_); unpack8(ghB, hz_); unpack8(ghC, hn_);
    unpack8(hpv, hp_);
    float hv8[8], av8[8];
    #pragma unroll
    for (int i = 0; i < 8; ++i) {
        float rg = sigm(ir_[i] + hr_[i]);
        float z  = sigm(iz_[i] + hz_[i]);
        float n  = tanhf(in_[i] + rg*hn_[i]);
        hv8[i] = (1.f - z)*n + z*hp_[i];
        av8[i] = fmaxf(hv8[i], 0.f);
    }
    if (LAST) {
        *reinterpret_cast<float4*>(&actout[r*EMB + e0])     = make_float4(av8[0],av8[1],av8[2],av8[3]);
        *reinterpret_cast<float4*>(&actout[r*EMB + e0 + 4]) = make_float4(av8[4],av8[5],av8[6],av8[7]);
    }
    uint4 hb, ab;
    hb.x = pk2(hv8[0],hv8[1]); hb.y = pk2(hv8[2],hv8[3]);
    hb.z = pk2(hv8[4],hv8[5]); hb.w = pk2(hv8[6],hv8[7]);
    ab.x = pk2(av8[0],av8[1]); ab.y = pk2(av8[2],av8[3]);
    ab.z = pk2(av8[4],av8[5]); ab.w = pk2(av8[6],av8[7]);
    *reinterpret_cast<uint4*>(&hbf[r*EMB + e0])   = hb;
    *reinterpret_cast<uint4*>(&actbf[r*EMB + e0]) = ab;
    float pc = 0.f, pn = 0.f;
    float4 w1a = *reinterpret_cast<const float4*>(&nextW[EMB + e0]);
    float4 w1b = *reinterpret_cast<const float4*>(&nextW[EMB + e0 + 4]);
    pn = av8[0]*w1a.x + av8[1]*w1a.y + av8[2]*w1a.z + av8[3]*w1a.w
       + av8[4]*w1b.x + av8[5]*w1b.y + av8[6]*w1b.z + av8[7]*w1b.w;
    if (!LAST) {
        float4 w0a = *reinterpret_cast<const float4*>(&nextW[e0]);
        float4 w0b = *reinterpret_cast<const float4*>(&nextW[e0 + 4]);
        pc = av8[0]*w0a.x + av8[1]*w0a.y + av8[2]*w0a.z + av8[3]*w0a.w
           + av8[4]*w0b.x + av8[5]*w0b.y + av8[6]*w0b.z + av8[7]*w0b.w;
    }
    #pragma unroll
    for (int off = 16; off; off >>= 1) {
        pn += __shfl_xor(pn, off, 32);
        if (!LAST) pc += __shfl_xor(pc, off, 32);
    }
    if (sub == 0) {
        if (!LAST) cdotO[r] = pc;
        ndotO[r] = pn;
    }
    if (LAST) {
        const float mk = mask[r];
        #pragma unroll
        for (int i = 0; i < 8; ++i) sred[row][e0 + i] = av8[i] * mk;
        __syncthreads();
        if (tid < 256) {
            float s = 0.f;
            #pragma unroll
            for (int rr = 0; rr < 16; ++rr) s += sred[rr][tid];
            atomicAdd(&seqfeatA[(blockIdx.x >> 5)*EMB + tid], s);
        }
    }
}

// ---- seqpvtf: per-strip tf tile via MFMA + cmol + softmax + PV (R15-proven).
__global__ __launch_bounds__(256) void seqpvtf_kernel(
    const float* __restrict__ ad, const float* __restrict__ mask,
    const float* __restrict__ saB, const float* __restrict__ saW,
    const float* __restrict__ seqfeat,
    const ushort* __restrict__ actbf, const ushort* __restrict__ satWbf,
    const float* __restrict__ satB,
    float* __restrict__ partial)
{
    const int st = blockIdx.x, b = blockIdx.y;
    const int tid = threadIdx.x;
    __shared__ ushort As[32][256];
    __shared__ float tf_s[32][256];
    __shared__ float w_s[SEQ];
    __shared__ float red[256];
    const int r0 = b*SEQ + st*32;

    {   // stage act strip swizzled
        #pragma unroll
        for (int i = 0; i < 4; ++i) {
            const int row = (tid >> 5) + i*8, c = tid & 31;
            uint4 v = *reinterpret_cast<const uint4*>(&actbf[(size_t)(r0+row)*EMB + (c<<3)]);
            *reinterpret_cast<uint4*>(&As[row][(c ^ (row&7)) << 3]) = v;
        }
    }
    red[tid] = fmaxf(seqfeat[b*EMB + tid], 0.f) * saW[tid];
    __syncthreads();
    for (int off = 128; off; off >>= 1) {
        if (tid < off) red[tid] += red[tid + off];
        __syncthreads();
    }
    const float cb = red[0];
    __syncthreads();
    float mk0 = mask[b*SEQ + tid], mk1 = mask[b*SEQ + 256 + tid];
    float bb = saB[0];
    float s0 = lrelu(cb + ad[b*SEQ + tid] + bb)       + (mk0 == 0.f ? NEGV : 0.f);
    float s1 = lrelu(cb + ad[b*SEQ + 256 + tid] + bb) + (mk1 == 0.f ? NEGV : 0.f);
    red[tid] = fmaxf(s0, s1); __syncthreads();
    for (int off = 128; off; off >>= 1) {
        if (tid < off) red[tid] = fmaxf(red[tid], red[tid + off]);
        __syncthreads();
    }
    float m = red[0]; __syncthreads();
    float e0v = expf(s0 - m), e1v = expf(s1 - m);
    red[tid] = e0v + e1v; __syncthreads();
    for (int off = 128; off; off >>= 1) {
        if (tid < off) red[tid] += red[tid + off];
        __syncthreads();
    }
    float inv = 1.f / red[0];
    w_s[tid]       = e0v * inv * mk0;
    w_s[tid + 256] = e1v * inv * mk1;
    __syncthreads();

    {   // tf tile: M=32 (2 sub-tiles), N=256 (4 waves x 64), K=256
        const int wv = tid >> 6, lane = tid & 63;
        const int fr = lane & 15, grp = lane >> 4;
        f32x4 acc[2][4];
        #pragma unroll
        for (int mt = 0; mt < 2; ++mt)
            #pragma unroll
            for (int f = 0; f < 4; ++f) acc[mt][f] = (f32x4){0,0,0,0};
        #pragma unroll
        for (int kt = 0; kt < 8; ++kt) {
            short8 af[2];
            #pragma unroll
            for (int mt = 0; mt < 2; ++mt) {
                const int ar = (mt << 4) + fr;
                af[mt] = *reinterpret_cast<const short8*>(
                    &As[ar][((((kt<<2)+grp) ^ (ar&7)) << 3)]);
            }
            #pragma unroll
            for (int f = 0; f < 4; ++f) {
                const int col = (wv<<6) + (f<<4) + fr;
                short8 bv = *reinterpret_cast<const short8*>(
                    &satWbf[(size_t)col*EMB + (kt<<5) + (grp<<3)]);
                #pragma unroll
                for (int mt = 0; mt < 2; ++mt)
                    acc[mt][f] = __builtin_amdgcn_mfma_f32_16x16x32_bf16(
                        af[mt], bv, acc[mt][f], 0, 0, 0);
            }
        }
        #pragma unroll
        for (int f = 0; f < 4; ++f) {
            const int col = (wv<<6) + (f<<4) + fr;
            const float bias = satB[col];
            #pragma unroll
            for (int mt = 0; mt < 2; ++mt)
                #pragma unroll
                for (int j = 0; j < 4; ++j)
                    tf_s[(mt<<4) + (grp<<2) + j][col] = acc[mt][f][j] + bias;
        }
    }
    __syncthreads();
    {   // PV over the strip
        float acc = 0.f;
        const int s0i = st * 32;
        #pragma unroll 4
        for (int s = 0; s < 32; ++s)
            acc += w_s[s0i + s] * tf_s[s][tid];
        partial[((size_t)b*16 + st)*EMB + tid] = acc;
    }
}

// Fused tail GRU step. Grid 32: (b, quarter q). 512 thr, 8 waves.
template<int T0>
__global__ __launch_bounds__(512) void seqstep_kernel(
    const float* __restrict__ partial, const float* __restrict__ sfin,
    const ushort* __restrict__ sgwihbf, const float* __restrict__ sgbih,
    const ushort* __restrict__ sgwhhbf, const float* __restrict__ sgbhh,
    float* __restrict__ sgi, float* __restrict__ sfout,
    float* __restrict__ actseq)
{
    const int b = blockIdx.x >> 2, q = blockIdx.x & 3;
    const int tid = threadIdx.x, lane = tid & 63, wv = tid >> 6;
    __shared__ float xs[EMB];
    __shared__ float hs[EMB];
    __shared__ float gis[192], ghs[192];
    if (tid < EMB) {
        hs[tid] = sfin[b*EMB + tid];
        if (T0) {
            float a = 0.f;
            #pragma unroll
            for (int st = 0; st < 16; ++st)
                a += partial[((size_t)b*16 + st)*EMB + tid];
            xs[tid] = elu1(a);
        }
    }
    if (!T0) {
        for (int l = tid; l < 192; l += 512) {
            int g = (l >> 6)*EMB + (q << 6) + (l & 63);
            gis[l] = sgi[b*G3 + g];
        }
    }
    __syncthreads();
    const int nrows = T0 ? 384 : 192;
    const int rpw = nrows >> 3;
    for (int i = 0; i < rpw; ++i) {
        const int l = wv * rpw + i;
        const int iswih = T0 && (l < 192);
        const int ll = (T0 && l >= 192) ? l - 192 : l;
        const int g = (ll >> 6)*EMB + (q << 6) + (ll & 63);
        const ushort* Wm = iswih ? sgwihbf : sgwhhbf;
        ushort4 w4 = *reinterpret_cast<const ushort4*>(&Wm[(size_t)g*EMB + (lane << 2)]);
        float4 x4 = *reinterpret_cast<const float4*>(iswih ? &xs[lane << 2] : &hs[lane << 2]);
        float d = bf2f(w4.x)*x4.x + bf2f(w4.y)*x4.y + bf2f(w4.z)*x4.z + bf2f(w4.w)*x4.w;
        #pragma unroll
        for (int off = 32; off; off >>= 1) d += __shfl_xor(d, off, 64);
        if (lane == 0) {
            if (iswih) {
                d += sgbih[g];
                gis[ll] = d;
                sgi[b*G3 + g] = d;
            } else {
                ghs[ll] = d + sgbhh[g];
            }
        }
    }
    __syncthreads();
    if (tid < 64) {
        const int e = (q << 6) + tid;
        float rg = sigm(gis[tid]       + ghs[tid]);
        float z  = sigm(gis[64 + tid]  + ghs[64 + tid]);
        float n  = tanhf(gis[128 + tid] + rg*ghs[128 + tid]);
        float hv = (1.f - z)*n + z*hs[e];
        sfout[b*EMB + e]  = hv;
        actseq[b*EMB + e] = fmaxf(hv, 0.f);
    }
}

extern "C" void kernel_launch(void* const* d_in, const int* in_sizes, int n_in,
                              void* d_out, int out_size, void* d_ws, size_t ws_size,
                              hipStream_t stream) {
    (void)in_sizes; (void)n_in; (void)out_size; (void)ws_size;
    const float* amino  = (const float*)d_in[0];
    const float* mask   = (const float*)d_in[1];
    const float* embW   = (const float*)d_in[2];
    const float* embB   = (const float*)d_in[3];
    const float* nbW    = (const float*)d_in[4];
    const float* nbB    = (const float*)d_in[5];
    const float* alignW = (const float*)d_in[6];
    const float* alignB = (const float*)d_in[7];
    const float* attW   = (const float*)d_in[8];
    const float* attB   = (const float*)d_in[9];
    const float* gwih   = (const float*)d_in[10];
    const float* gwhh   = (const float*)d_in[11];
    const float* gbih   = (const float*)d_in[12];
    const float* gbhh   = (const float*)d_in[13];
    const float* saW    = (const float*)d_in[14];
    const float* saB    = (const float*)d_in[15];
    const float* satW   = (const float*)d_in[16];
    const float* satB   = (const float*)d_in[17];
    const float* sgwih  = (const float*)d_in[18];
    const float* sgbih  = (const float*)d_in[19];
    const float* sgwhh  = (const float*)d_in[20];
    const float* sgbhh  = (const float*)d_in[21];
    const int*   idx    = (const int*)d_in[22];

    char* cur = (char*)d_ws;
    auto alloc = [&](size_t bytes) -> char* {
        char* p = cur; cur += (bytes + 255) & ~(size_t)255; return p;
    };
    // seqfeat, cdot, ndot contiguous (zeroed as one 40KB range by convert_core)
    float* seqfeat = (float*)alloc(BSZ*EMB*4);
    float* cdot    = (float*)alloc(BS*4);
    float* ndot    = (float*)alloc(BS*4);        // doubles as ad
    float* sf2     = (float*)alloc(BSZ*EMB*4);
    float* sgi     = (float*)alloc(BSZ*G3*4);
    float* partial = (float*)alloc((size_t)BSZ*16*EMB*4);
    ushort* aminobf  = (ushort*)alloc((size_t)BS*INITD*2);
    ushort* featbf   = (ushort*)alloc((size_t)BS*EMB*2);
    ushort* nbasebf  = (ushort*)alloc((size_t)BS*EMB*2);
    ushort* actbf    = (ushort*)alloc((size_t)BS*EMB*2);
    ushort* hbf      = (ushort*)alloc((size_t)BS*EMB*2);
    ushort* ctxbf    = (ushort*)alloc((size_t)BS*EMB*2);
    ushort* gibf     = (ushort*)alloc((size_t)BS*G3*2);
    ushort* ghbf     = (ushort*)alloc((size_t)BS*G3*2);
    ushort* embWbf   = (ushort*)alloc((size_t)EMB*INITD*2);
    ushort* nbWbf    = (ushort*)alloc((size_t)EMB*INITD*2);
    ushort* attWbf   = (ushort*)alloc((size_t)3*EMB*EMB*2);
    ushort* gwihbf   = (ushort*)alloc((size_t)3*G3*EMB*2);
    ushort* gwhhbf   = (ushort*)alloc((size_t)3*G3*EMB*2);
    ushort* satWbf   = (ushort*)alloc((size_t)EMB*EMB*2);
    ushort* sgwihbf  = (ushort*)alloc((size_t)G3*EMB*2);
    ushort* sgwhhbf  = (ushort*)alloc((size_t)G3*EMB*2);

    float* out    = (float*)d_out;
    float* actseq = out;               // (B,E)
    float* act    = out + BSZ*EMB;     // (B,S,E)

    convert_core<<<1280, 256, 0, stream>>>(
        amino, aminobf, embW, embWbf, nbW, nbWbf, seqfeat);

    featnbase_kernel<<<384, 256, 0, stream>>>(
        aminobf, embWbf, embB, featbf, nbWbf, nbB, nbasebf,
        alignW, cdot, ndot,
        attW, attWbf, gwih, gwihbf, gwhh, gwhhbf,
        satW, satWbf, sgwih, sgwihbf, sgwhh, sgwhhbf);

    for (int d = 0; d < 3; ++d) {
        const ushort* nbrbf   = (d == 0) ? nbasebf : actbf;
        const ushort* hprevbf = (d == 0) ? featbf  : hbf;
        gatherattend_kernel<<<BS/16, 512, 0, stream>>>(
            cdot, ndot, idx, nbrbf, alignB + d,
            attWbf + (size_t)d*EMB*EMB, attB + d*EMB, ctxbf);
        gigh_kernel<<<768, 256, 0, stream>>>(
            ctxbf, gwihbf + (size_t)d*G3*EMB, gbih + d*G3, gibf,
            hprevbf, gwhhbf + (size_t)d*G3*EMB, gbhh + d*G3, ghbf);
        if (d < 2) {
            grudot_kernel<0><<<BS/16, 512, 0, stream>>>(
                gibf, ghbf, hprevbf, alignW + (d+1)*2*EMB, mask,
                hbf, act, actbf, cdot, ndot, seqfeat);
        } else {
            grudot_kernel<1><<<BS/16, 512, 0, stream>>>(
                gibf, ghbf, hprevbf, saW, mask,
                hbf, act, actbf, cdot, ndot, seqfeat);   // ndot <- ad
        }
    }

    seqpvtf_kernel<<<dim3(16, BSZ), 256, 0, stream>>>(
        ndot, mask, saB, saW, seqfeat, actbf, satWbf, satB, partial);
    seqstep_kernel<1><<<32, 512, 0, stream>>>(
        partial, seqfeat, sgwihbf, sgbih, sgwhhbf, sgbhh, sgi, sf2, actseq);
    seqstep_kernel<0><<<32, 512, 0, stream>>>(
        partial, sf2, sgwihbf, sgbih, sgwhhbf, sgbhh, sgi, seqfeat, actseq);
}